// Round 3
// baseline (302.001 us; speedup 1.0000x reference)
//
#include <hip/hip_runtime.h>

// QuantumAttentionMechanism on MI355X (gfx950)
// B=4, S=1024, D=1024, H=16, NQ=8, HEAD_DIM=64, ALPHA=0.7
//
// Math simplifications (exact up to fp rounding):
//   classical.mean(h) = (Q . K over full D) / (H*sqrt(HEAD_DIM)) = dot/128
//   entropy(i,j) = log(Z) - (Sa_i + Sb_j)/Z,  Z = A_i + B_j  (per-row aggregates, NQ=8)
//   attended = attn @ V (full D), output = attended @ Wo^T + bo.
//
// GEMM core: 256x256 tile, BK=64, 8 waves (512 thr), 8-phase schedule with
// counted vmcnt(4) (T3+T4), LDS XOR swizzle slot^=(row>>1)&3 (T2, both-sides
// with pre-swizzled global source for global_load_lds), setprio around MFMA (T5).
// K-split half-tiles [256][32] per kk; phases = (nh,kk); stages follow last-read:
//   ph1:Ak1(t+1) ph2:Bk1(t+1) ph3:Ak0(t+2) ph4:Bk0(t+2)+VM
//   ph5:Ak1(t+2) ph6:Bk1(t+2) ph7:Ak0(t+3) ph8:Bk0(t+3)+VM
// vmcnt(4) at ph4 covers all of tile t+1 (newest outstanding = ph3,ph4 = t+2 halves);
// vmcnt(4) at ph8 covers all of tile t+2. Stage into a slot is always >=1 phase
// after its last LDS-read's end-barrier (all waves' reads drained into regs).

typedef float f32x4 __attribute__((ext_vector_type(4)));
typedef short s16x8 __attribute__((ext_vector_type(8)));
typedef unsigned short u16;

#define Bc 4
#define Sc 1024
#define Dc 1024
#define NTOK (Bc * Sc)          // 4096
#define CSCALE (0.7f / 128.0f)  // ALPHA / (H*sqrt(HEAD_DIM))
#define ESCALE 0.3f             // 1-ALPHA

typedef void __attribute__((address_space(1))) as1_void;
typedef void __attribute__((address_space(3))) as3_void;

__device__ __forceinline__ u16 f2b(float f) {  // fp32 -> bf16 RNE
  union { float f; unsigned u; } v; v.f = f;
  unsigned r = v.u + 0x7fffu + ((v.u >> 16) & 1u);
  return (u16)(r >> 16);
}

// ---------------- cast fp32 -> bf16, vectorized ----------------
__global__ __launch_bounds__(256) void cast_bf16(const float* __restrict__ in,
                                                 u16* __restrict__ out, int n4) {
  int i = blockIdx.x * 256 + threadIdx.x;
  if (i >= n4) return;
  float4 v = reinterpret_cast<const float4*>(in)[i];
  ushort4 o = make_ushort4(f2b(v.x), f2b(v.y), f2b(v.z), f2b(v.w));
  reinterpret_cast<ushort4*>(out)[i] = o;
}

// ---------------- per-row entropy aggregates ----------------
__global__ __launch_bounds__(256) void ent_agg(const float* __restrict__ q,
                                               const float* __restrict__ k,
                                               float* __restrict__ agg) {
  int r = blockIdx.x * 256 + threadIdx.x;
  if (r >= 2 * NTOK) return;
  const float* src = (r < NTOK) ? (q + (size_t)r * Dc) : (k + (size_t)(r - NTOK) * Dc);
  float A = 0.f, Sv = 0.f;
#pragma unroll
  for (int m = 0; m < 8; ++m) {
    float e = tanhf(src[m]);
    float a = __expf(e);
    A += a; Sv += a * e;
  }
  if (r < NTOK) { agg[r] = A; agg[NTOK + r] = Sv; }
  else          { agg[NTOK + r] = A; agg[3 * NTOK + (r - NTOK)] = Sv; }
}

// ---------------- 256x256 8-phase GEMM core (K=1024, lda=ldb=1024) ----------------
__device__ __forceinline__ void stage2(const u16* base0, const u16* base1, int koff,
                                       u16* dst, int tid) {
  __builtin_amdgcn_global_load_lds((const as1_void*)(base0 + koff),
                                   (as3_void*)(dst + tid * 8), 16, 0, 0);
  __builtin_amdgcn_global_load_lds((const as1_void*)(base1 + koff),
                                   (as3_void*)(dst + (tid + 512) * 8), 16, 0, 0);
}

#define PHASE(BUF, KK, NH, SB0, SB1, DST, KOFF, VM) do {                          \
    if (NH == 0) {                                                                \
      _Pragma("unroll") for (int i = 0; i < 8; ++i)                               \
        a_fr[i] = *reinterpret_cast<const s16x8*>(&L[BUF][0][KK][aoff[i]]);       \
    }                                                                             \
    s16x8 b_fr[2];                                                                \
    _Pragma("unroll") for (int j = 0; j < 2; ++j)                                 \
      b_fr[j] = *reinterpret_cast<const s16x8*>(&L[BUF][1][KK][boff[NH][j]]);     \
    stage2(SB0, SB1, KOFF, DST, tid);                                             \
    __builtin_amdgcn_s_barrier();                                                 \
    __builtin_amdgcn_s_setprio(1);                                                \
    _Pragma("unroll") for (int i = 0; i < 8; ++i) {                               \
      acc[i][NH*2+0] = __builtin_amdgcn_mfma_f32_16x16x32_bf16(a_fr[i], b_fr[0], acc[i][NH*2+0], 0, 0, 0); \
      acc[i][NH*2+1] = __builtin_amdgcn_mfma_f32_16x16x32_bf16(a_fr[i], b_fr[1], acc[i][NH*2+1], 0, 0, 0); \
    }                                                                             \
    __builtin_amdgcn_s_setprio(0);                                                \
    if (VM) asm volatile("s_waitcnt vmcnt(4)" ::: "memory");                      \
    __builtin_amdgcn_s_barrier();                                                 \
    __builtin_amdgcn_sched_barrier(0);                                            \
  } while (0)

// acc[8][4]: per-wave 128x64 C block. wr=wave>>2 (M half), wc=wave&3 (N quarter).
__device__ __forceinline__ void gemm256(const u16* __restrict__ A, const u16* __restrict__ Bt,
                                        int row0, int col0, f32x4 acc[8][4]) {
  __shared__ u16 L[2][2][2][8192];  // [buf][A=0/B=1][kk][256*32], 128 KiB
  const int tid  = threadIdx.x;
  const int lane = tid & 63;
  const int wave = tid >> 6;
  const int wr = wave >> 2, wc = wave & 3;
  const int fr = lane & 15, g = lane >> 4;

  // staging bases (pre-swizzled global source: srcslot = slot ^ ((row>>1)&3))
  const int r0s = tid >> 2;
  const int sl0 = (tid & 3) ^ ((r0s >> 1) & 3);
  const int r1s = r0s + 128;
  const int sl1 = (tid & 3) ^ ((r1s >> 1) & 3);
  const u16* sa0 = A  + (size_t)(row0 + r0s) * 1024 + sl0 * 8;
  const u16* sa1 = A  + (size_t)(row0 + r1s) * 1024 + sl1 * 8;
  const u16* sb0 = Bt + (size_t)(col0 + r0s) * 1024 + sl0 * 8;
  const u16* sb1 = Bt + (size_t)(col0 + r1s) * 1024 + sl1 * 8;

  // fragment LDS offsets (swizzled read side)
  int aoff[8], boff[2][2];
#pragma unroll
  for (int i = 0; i < 8; ++i) {
    int row = wr * 128 + i * 16 + fr;
    aoff[i] = row * 32 + ((g ^ ((row >> 1) & 3)) << 3);
  }
#pragma unroll
  for (int nh = 0; nh < 2; ++nh)
#pragma unroll
    for (int j = 0; j < 2; ++j) {
      int row = wc * 64 + nh * 32 + j * 16 + fr;
      boff[nh][j] = row * 32 + ((g ^ ((row >> 1) & 3)) << 3);
    }

  // prologue: t0 all 4 halves, t1 kk0 halves. 12 loads; keep newest 4 in flight.
  stage2(sa0, sa1, 0,  &L[0][0][0][0], tid);
  stage2(sb0, sb1, 0,  &L[0][1][0][0], tid);
  stage2(sa0, sa1, 32, &L[0][0][1][0], tid);
  stage2(sb0, sb1, 32, &L[0][1][1][0], tid);
  stage2(sa0, sa1, 64, &L[1][0][0][0], tid);
  stage2(sb0, sb1, 64, &L[1][1][0][0], tid);
  asm volatile("s_waitcnt vmcnt(4)" ::: "memory");
  __builtin_amdgcn_s_barrier();
  __builtin_amdgcn_sched_barrier(0);

  s16x8 a_fr[8];
  for (int u = 0; u < 8; ++u) {
    const int t = 2 * u;
    const int k1 = (t + 1) * 64, k2 = ((t + 2) & 15) * 64, k3 = ((t + 3) & 15) * 64;
    PHASE(0, 0, 0, sa0, sa1, &L[1][0][1][0], k1 + 32, false);  // ph1: stage Ak1(t+1)
    PHASE(0, 0, 1, sb0, sb1, &L[1][1][1][0], k1 + 32, false);  // ph2: Bk1(t+1)
    PHASE(0, 1, 0, sa0, sa1, &L[0][0][0][0], k2,      false);  // ph3: Ak0(t+2)
    PHASE(0, 1, 1, sb0, sb1, &L[0][1][0][0], k2,      true);   // ph4: Bk0(t+2) +vmcnt
    PHASE(1, 0, 0, sa0, sa1, &L[0][0][1][0], k2 + 32, false);  // ph5: Ak1(t+2)
    PHASE(1, 0, 1, sb0, sb1, &L[0][1][1][0], k2 + 32, false);  // ph6: Bk1(t+2)
    PHASE(1, 1, 0, sa0, sa1, &L[1][0][0][0], k3,      false);  // ph7: Ak0(t+3)
    PHASE(1, 1, 1, sb0, sb1, &L[1][1][0][0], k3,      true);   // ph8: Bk0(t+3) +vmcnt
  }
}

// ---------------- QKV projections (z=0:Q, 1:K, 2:V-transposed) ----------------
__global__ __launch_bounds__(512, 2) void gemm_proj256(const u16* __restrict__ Xall,
                                                       const u16* __restrict__ Wall,
                                                       const float* __restrict__ biasq,
                                                       const float* __restrict__ biask,
                                                       const float* __restrict__ biasv,
                                                       u16* __restrict__ QKout,
                                                       u16* __restrict__ Vt) {
  const int z = blockIdx.z;
  const int row0 = blockIdx.x * 256, col0 = blockIdx.y * 256;
  const u16* A  = Xall + (size_t)z * NTOK * Dc;
  const u16* Bt = Wall + (size_t)z * Dc * Dc;
  f32x4 acc[8][4] = {};
  gemm256(A, Bt, row0, col0, acc);

  const int lane = threadIdx.x & 63, wave = threadIdx.x >> 6;
  const int wr = wave >> 2, wc = wave & 3;
  const int cr = (lane >> 4) * 4, cc = lane & 15;
  const float* bias = (z == 0) ? biasq : (z == 1) ? biask : biasv;
#pragma unroll
  for (int j = 0; j < 4; ++j) {
    const int gc = col0 + wc * 64 + j * 16 + cc;
    const float bb = bias[gc];
#pragma unroll
    for (int i = 0; i < 8; ++i) {
      const int gr = row0 + wr * 128 + i * 16 + cr;
      f32x4 v = acc[i][j];
      if (z < 2) {
        u16* dst = QKout + (size_t)z * NTOK * Dc + (size_t)gr * Dc + gc;
#pragma unroll
        for (int r = 0; r < 4; ++r) dst[(size_t)r * Dc] = f2b(v[r] + bb);
      } else {
        const int b = gr >> 10, t = gr & (Sc - 1);  // t multiple of 4
        ushort4 o = make_ushort4(f2b(v[0] + bb), f2b(v[1] + bb), f2b(v[2] + bb), f2b(v[3] + bb));
        *reinterpret_cast<ushort4*>(Vt + (size_t)b * Dc * Sc + (size_t)gc * Sc + t) = o;
      }
    }
  }
}

// ---------------- scores GEMM + entropy epilogue -> combined fp32 ----------------
__global__ __launch_bounds__(512, 2) void gemm_scores256(const u16* __restrict__ Qb,
                                                         const u16* __restrict__ Kb,
                                                         const float* __restrict__ agg,
                                                         float* __restrict__ comb) {
  const int z = blockIdx.z;
  const int row0 = blockIdx.x * 256, col0 = blockIdx.y * 256;
  const u16* A  = Qb + (size_t)z * Sc * Dc;
  const u16* Bt = Kb + (size_t)z * Sc * Dc;
  f32x4 acc[8][4] = {};
  gemm256(A, Bt, row0, col0, acc);

  const int lane = threadIdx.x & 63, wave = threadIdx.x >> 6;
  const int wr = wave >> 2, wc = wave & 3;
  const int cr = (lane >> 4) * 4, cc = lane & 15;
  const float* qA = agg + (size_t)z * Sc;
  const float* qS = agg + NTOK + (size_t)z * Sc;
  const float* kA = agg + 2 * NTOK + (size_t)z * Sc;
  const float* kS = agg + 3 * NTOK + (size_t)z * Sc;
  float* C = comb + (size_t)z * Sc * Sc;
#pragma unroll
  for (int j = 0; j < 4; ++j) {
    const int gc = col0 + wc * 64 + j * 16 + cc;
    const float kAv = kA[gc], kSv = kS[gc];
#pragma unroll
    for (int i = 0; i < 8; ++i) {
      const int gr = row0 + wr * 128 + i * 16 + cr;
      f32x4 v = acc[i][j];
#pragma unroll
      for (int r = 0; r < 4; ++r) {
        const int s = gr + r;
        const float Z = qA[s] + kAv;
        const float ent = __logf(Z) - (qS[s] + kSv) / Z;
        C[(size_t)s * Sc + gc] = CSCALE * v[r] + ESCALE * ent;
      }
    }
  }
}

// ---------------- row softmax: comb -> attn fp32 (d_out) + attn bf16 (ws) ----------------
__global__ __launch_bounds__(256) void softmax_row(const float* __restrict__ comb,
                                                   float* __restrict__ attn_f,
                                                   u16* __restrict__ attn_b) {
  const int row = blockIdx.x;
  const int t = threadIdx.x;
  const float* src = comb + (size_t)row * Sc;
  float4 v = reinterpret_cast<const float4*>(src)[t];
  float m = fmaxf(fmaxf(v.x, v.y), fmaxf(v.z, v.w));
#pragma unroll
  for (int off = 1; off < 64; off <<= 1) m = fmaxf(m, __shfl_xor(m, off));
  __shared__ float red[8];
  if ((t & 63) == 0) red[t >> 6] = m;
  __syncthreads();
  m = fmaxf(fmaxf(red[0], red[1]), fmaxf(red[2], red[3]));
  float e0 = __expf(v.x - m), e1 = __expf(v.y - m), e2 = __expf(v.z - m), e3 = __expf(v.w - m);
  float s = e0 + e1 + e2 + e3;
#pragma unroll
  for (int off = 1; off < 64; off <<= 1) s += __shfl_xor(s, off);
  if ((t & 63) == 0) red[4 + (t >> 6)] = s;
  __syncthreads();
  s = red[4] + red[5] + red[6] + red[7];
  const float inv = 1.f / s;
  float4 o = make_float4(e0 * inv, e1 * inv, e2 * inv, e3 * inv);
  reinterpret_cast<float4*>(attn_f + (size_t)row * Sc)[t] = o;
  ushort4 ob = make_ushort4(f2b(o.x), f2b(o.y), f2b(o.z), f2b(o.w));
  reinterpret_cast<ushort4*>(attn_b + (size_t)row * Sc)[t] = ob;
}

// ---------------- attended = attn @ V  (Bt = Vt[b][d][t]) ----------------
__global__ __launch_bounds__(512, 2) void gemm_av256(const u16* __restrict__ attnb,
                                                     const u16* __restrict__ Vt,
                                                     u16* __restrict__ att) {
  const int z = blockIdx.z;
  const int row0 = blockIdx.x * 256, col0 = blockIdx.y * 256;
  const u16* A  = attnb + (size_t)z * Sc * Sc;
  const u16* Bt = Vt + (size_t)z * Dc * Sc;
  f32x4 acc[8][4] = {};
  gemm256(A, Bt, row0, col0, acc);

  const int lane = threadIdx.x & 63, wave = threadIdx.x >> 6;
  const int wr = wave >> 2, wc = wave & 3;
  const int cr = (lane >> 4) * 4, cc = lane & 15;
  u16* C = att + (size_t)z * Sc * Dc;
#pragma unroll
  for (int j = 0; j < 4; ++j) {
    const int gc = col0 + wc * 64 + j * 16 + cc;
#pragma unroll
    for (int i = 0; i < 8; ++i) {
      const int gr = row0 + wr * 128 + i * 16 + cr;
      f32x4 v = acc[i][j];
#pragma unroll
      for (int r = 0; r < 4; ++r) C[(size_t)(gr + r) * Dc + gc] = f2b(v[r]);
    }
  }
}

// ---------------- output = attended @ Wo^T + bo -> fp32 d_out ----------------
__global__ __launch_bounds__(512, 2) void gemm_out256(const u16* __restrict__ att,
                                                      const u16* __restrict__ Wob,
                                                      const float* __restrict__ bo,
                                                      float* __restrict__ out) {
  const int row0 = blockIdx.x * 256, col0 = blockIdx.y * 256;
  f32x4 acc[8][4] = {};
  gemm256(att, Wob, row0, col0, acc);

  const int lane = threadIdx.x & 63, wave = threadIdx.x >> 6;
  const int wr = wave >> 2, wc = wave & 3;
  const int cr = (lane >> 4) * 4, cc = lane & 15;
#pragma unroll
  for (int j = 0; j < 4; ++j) {
    const int gc = col0 + wc * 64 + j * 16 + cc;
    const float bb = bo[gc];
#pragma unroll
    for (int i = 0; i < 8; ++i) {
      const int gr = row0 + wr * 128 + i * 16 + cr;
      f32x4 v = acc[i][j];
#pragma unroll
      for (int r = 0; r < 4; ++r) out[(size_t)(gr + r) * Dc + gc] = v[r] + bb;
    }
  }
}

extern "C" void kernel_launch(void* const* d_in, const int* in_sizes, int n_in,
                              void* d_out, int out_size, void* d_ws, size_t ws_size,
                              hipStream_t stream) {
  const float* query = (const float*)d_in[0];
  const float* key   = (const float*)d_in[1];
  const float* value = (const float*)d_in[2];
  const float* Wq = (const float*)d_in[3];
  const float* bq = (const float*)d_in[4];
  const float* Wk = (const float*)d_in[5];
  const float* bk = (const float*)d_in[6];
  const float* Wv = (const float*)d_in[7];
  const float* bv = (const float*)d_in[8];
  const float* Wo = (const float*)d_in[9];
  const float* bo = (const float*)d_in[10];

  float* out    = (float*)d_out;                    // [B,S,D]
  float* attn_f = out + (size_t)NTOK * Dc;          // [B,S,S]

  char* w = (char*)d_ws;
  const size_t MB = 1ull << 20;
  // Lifetime-overlaid layout (~56 MB):
  //  [0,24)MB : qx,kx,vx; then comb fp32 [0,16) + attnb [16,24)
  //  [24,40)MB: Qb,Kb; then attended overlays [24,32)
  //  [40,48)MB: Vt
  //  [48,56)MB: Wq,Wk,Wv,Wo bf16
  //  [56,..)  : entropy aggregates (64 KB)
  u16* qx = (u16*)(w);
  u16* kx = (u16*)(w + 8 * MB);
  u16* vx = (u16*)(w + 16 * MB);
  float* comb = (float*)(w);
  u16* attnb  = (u16*)(w + 16 * MB);
  u16* Qb = (u16*)(w + 24 * MB);            // Kb = Qb + NTOK*Dc
  u16* attended = (u16*)(w + 24 * MB);
  u16* Vt = (u16*)(w + 40 * MB);
  u16* Wb = (u16*)(w + 48 * MB);            // wq,wk,wv,wo contiguous (2MB each)
  float* agg = (float*)(w + 56 * MB);

  const int n4tok = NTOK * Dc / 4;  // 1048576
  const int n4w   = Dc * Dc / 4;    // 262144

  // 1. casts
  cast_bf16<<<n4tok / 256, 256, 0, stream>>>(query, qx, n4tok);
  cast_bf16<<<n4tok / 256, 256, 0, stream>>>(key,   kx, n4tok);
  cast_bf16<<<n4tok / 256, 256, 0, stream>>>(value, vx, n4tok);
  cast_bf16<<<n4w / 256, 256, 0, stream>>>(Wq, Wb + 0ull * Dc * Dc, n4w);
  cast_bf16<<<n4w / 256, 256, 0, stream>>>(Wk, Wb + 1ull * Dc * Dc, n4w);
  cast_bf16<<<n4w / 256, 256, 0, stream>>>(Wv, Wb + 2ull * Dc * Dc, n4w);
  cast_bf16<<<n4w / 256, 256, 0, stream>>>(Wo, Wb + 3ull * Dc * Dc, n4w);

  // 2. entropy row aggregates
  ent_agg<<<(2 * NTOK) / 256, 256, 0, stream>>>(query, key, agg);

  // 3. Q/K/V projections (z=0,1,2), V written transposed
  gemm_proj256<<<dim3(16, 4, 3), 512, 0, stream>>>(qx, Wb, bq, bk, bv, Qb, Vt);

  // 4. combined scores
  gemm_scores256<<<dim3(4, 4, 4), 512, 0, stream>>>(Qb, Qb + (size_t)NTOK * Dc, agg, comb);

  // 5. softmax rows -> attn (fp32 to d_out, bf16 to ws)
  softmax_row<<<NTOK, 256, 0, stream>>>(comb, attn_f, attnb);

  // 6. attended = attn @ V
  gemm_av256<<<dim3(4, 4, 4), 512, 0, stream>>>(attnb, Vt, attended);

  // 7. output = attended @ Wo^T + bo
  gemm_out256<<<dim3(16, 4, 1), 512, 0, stream>>>(attended, Wb + 3ull * Dc * Dc, bo, out);

  (void)in_sizes; (void)n_in; (void)out_size; (void)ws_size;
}

// Round 4
// 245.671 us; speedup vs baseline: 1.2293x; 1.2293x over previous
//
#include <hip/hip_runtime.h>

// QuantumAttentionMechanism on MI355X (gfx950)
// B=4, S=1024, D=1024, H=16, NQ=8, HEAD_DIM=64, ALPHA=0.7
//
// Math simplifications (exact up to fp rounding):
//   classical.mean(h) = (Q . K over full D) / (H*sqrt(HEAD_DIM)) = dot/128
//   entropy(i,j) = log(Z) - (Sa_i + Sb_j)/Z,  Z = A_i + B_j  (per-row aggregates, NQ=8)
//   attended = attn @ V (full D), output = attended @ Wo^T + bo.
//
// GEMM core (round 4): minimum 2-phase, double-buffered LDS, BK=32, 4 waves.
//   per K-step: STAGE(next buf) -> ds_read+MFMA(cur buf) -> vmcnt(0)+s_barrier.
//   One barrier per K-step; stage latency hidden under MFMAs + 2-3 blocks/CU TLP.
// T2 involution swizzle (slot ^= (row>>1)&3) on both stage-source and ds_read
// (bank conflicts measured 0 in round 3). Bijective XCD block swizzle (T1).
// Tile sizes chosen for occupancy at 1024-shapes: proj 128x128 (768 blocks),
// scores/av/out 64x128 (512 blocks each).

typedef float f32x4 __attribute__((ext_vector_type(4)));
typedef short s16x8 __attribute__((ext_vector_type(8)));
typedef unsigned short u16;

#define Bc 4
#define Sc 1024
#define Dc 1024
#define NTOK (Bc * Sc)          // 4096
#define CSCALE (0.7f / 128.0f)  // ALPHA / (H*sqrt(HEAD_DIM))
#define ESCALE 0.3f             // 1-ALPHA

typedef void __attribute__((address_space(1))) as1_void;
typedef void __attribute__((address_space(3))) as3_void;

__device__ __forceinline__ u16 f2b(float f) {  // fp32 -> bf16 RNE
  union { float f; unsigned u; } v; v.f = f;
  unsigned r = v.u + 0x7fffu + ((v.u >> 16) & 1u);
  return (u16)(r >> 16);
}

__device__ __forceinline__ void xcd_map(int& bx, int& by, int& bz) {
  const int gx = gridDim.x, gy = gridDim.y;
  const int nwg = gx * gy * gridDim.z;        // all grids here are %8 == 0
  const int lid = blockIdx.x + gx * (blockIdx.y + gy * blockIdx.z);
  const int cpx = nwg >> 3;
  const int s = (lid & 7) * cpx + (lid >> 3);
  bx = s % gx; const int r = s / gx; by = r % gy; bz = r / gy;
}

// ---------------- cast fp32 -> bf16, vectorized ----------------
__global__ __launch_bounds__(256) void cast_bf16(const float* __restrict__ in,
                                                 u16* __restrict__ out, int n4) {
  int i = blockIdx.x * 256 + threadIdx.x;
  if (i >= n4) return;
  float4 v = reinterpret_cast<const float4*>(in)[i];
  ushort4 o = make_ushort4(f2b(v.x), f2b(v.y), f2b(v.z), f2b(v.w));
  reinterpret_cast<ushort4*>(out)[i] = o;
}

// ---------------- per-row entropy aggregates ----------------
__global__ __launch_bounds__(256) void ent_agg(const float* __restrict__ q,
                                               const float* __restrict__ k,
                                               float* __restrict__ agg) {
  int r = blockIdx.x * 256 + threadIdx.x;
  if (r >= 2 * NTOK) return;
  const float* src = (r < NTOK) ? (q + (size_t)r * Dc) : (k + (size_t)(r - NTOK) * Dc);
  float A = 0.f, Sv = 0.f;
#pragma unroll
  for (int m = 0; m < 8; ++m) {
    float e = tanhf(src[m]);
    float a = __expf(e);
    A += a; Sv += a * e;
  }
  if (r < NTOK) { agg[r] = A; agg[NTOK + r] = Sv; }
  else          { agg[NTOK + r] = A; agg[3 * NTOK + (r - NTOK)] = Sv; }
}

// ---------------- minimum-2-phase GEMM core: C[BM x 128] = A * Bt^T ----------------
// 256 threads, 4 waves as 2x2 (wave tile BM/2 x 64). BK=32, double-buffered LDS.
template<int BM>
__device__ __forceinline__ void gemm2(const u16* __restrict__ A, const u16* __restrict__ Bt,
                                      int K, int row0, int col0,
                                      f32x4 (*acc)[4]) {
  constexpr int MR = BM / 32;  // 128 -> 4, 64 -> 2
  __shared__ __align__(16) u16 LA[2][BM * 32];
  __shared__ __align__(16) u16 LB[2][128 * 32];
  const int tid = threadIdx.x;
  const int lane = tid & 63, wave = tid >> 6;
  const int wr = wave >> 1, wc = wave & 1;
  const int fr = lane & 15, g = lane >> 4;

  // stage addressing: LDS linear (r = ci>>2, slot = ci&3), global source pre-swizzled
  const int rA0 = tid >> 2;
  const int slA0 = (tid & 3) ^ ((rA0 >> 1) & 3);
  const u16* gA0 = A + (size_t)(row0 + rA0) * K + slA0 * 8;
  const u16* gA1 = nullptr;
  if constexpr (BM == 128) {
    const int rA1 = rA0 + 64;
    const int slA1 = (tid & 3) ^ ((rA1 >> 1) & 3);
    gA1 = A + (size_t)(row0 + rA1) * K + slA1 * 8;
  }
  const int rB1 = rA0 + 64;
  const int slB1 = (tid & 3) ^ ((rB1 >> 1) & 3);
  const u16* gB0 = Bt + (size_t)(col0 + rA0) * K + slA0 * 8;
  const u16* gB1 = Bt + (size_t)(col0 + rB1) * K + slB1 * 8;

  // swizzled ds_read offsets
  int aoff[MR], boff[4];
#pragma unroll
  for (int i = 0; i < MR; ++i) {
    const int row = wr * (MR * 16) + i * 16 + fr;
    aoff[i] = row * 32 + ((g ^ ((row >> 1) & 3)) << 3);
  }
#pragma unroll
  for (int j = 0; j < 4; ++j) {
    const int row = wc * 64 + j * 16 + fr;
    boff[j] = row * 32 + ((g ^ ((row >> 1) & 3)) << 3);
  }

  auto stage = [&](int buf, int kt) {
    const int ko = kt * 32;
    __builtin_amdgcn_global_load_lds((const as1_void*)(gA0 + ko),
                                     (as3_void*)(&LA[buf][tid * 8]), 16, 0, 0);
    if constexpr (BM == 128)
      __builtin_amdgcn_global_load_lds((const as1_void*)(gA1 + ko),
                                       (as3_void*)(&LA[buf][(256 + tid) * 8]), 16, 0, 0);
    __builtin_amdgcn_global_load_lds((const as1_void*)(gB0 + ko),
                                     (as3_void*)(&LB[buf][tid * 8]), 16, 0, 0);
    __builtin_amdgcn_global_load_lds((const as1_void*)(gB1 + ko),
                                     (as3_void*)(&LB[buf][(256 + tid) * 8]), 16, 0, 0);
  };

  const int nk = K >> 5;
  stage(0, 0);
  asm volatile("s_waitcnt vmcnt(0)" ::: "memory");
  __builtin_amdgcn_s_barrier();
  __builtin_amdgcn_sched_barrier(0);

  for (int kt = 0; kt < nk; ++kt) {
    const int cur = kt & 1;
    if (kt + 1 < nk) stage(cur ^ 1, kt + 1);
    s16x8 af[MR], bf[4];
#pragma unroll
    for (int i = 0; i < MR; ++i) af[i] = *reinterpret_cast<const s16x8*>(&LA[cur][aoff[i]]);
#pragma unroll
    for (int j = 0; j < 4; ++j) bf[j] = *reinterpret_cast<const s16x8*>(&LB[cur][boff[j]]);
#pragma unroll
    for (int i = 0; i < MR; ++i)
#pragma unroll
      for (int j = 0; j < 4; ++j)
        acc[i][j] = __builtin_amdgcn_mfma_f32_16x16x32_bf16(af[i], bf[j], acc[i][j], 0, 0, 0);
    if (kt + 1 < nk) {
      asm volatile("s_waitcnt vmcnt(0)" ::: "memory");  // next-buf stage complete
      __builtin_amdgcn_s_barrier();                     // all waves' reads of cur done
      __builtin_amdgcn_sched_barrier(0);
    }
  }
}

// ---------------- QKV projections (z=0:Q, 1:K, 2:V-transposed), 128x128 ----------------
__global__ __launch_bounds__(256, 4) void gemm_proj(const u16* __restrict__ Xall,
                                                    const u16* __restrict__ Wall,
                                                    const float* __restrict__ biasq,
                                                    const float* __restrict__ biask,
                                                    const float* __restrict__ biasv,
                                                    u16* __restrict__ QKout,
                                                    u16* __restrict__ Vt) {
  int bx, by, z; xcd_map(bx, by, z);
  const int row0 = bx * 128, col0 = by * 128;
  const u16* A  = Xall + (size_t)z * NTOK * Dc;
  const u16* Bt = Wall + (size_t)z * Dc * Dc;
  f32x4 acc[4][4] = {};
  gemm2<128>(A, Bt, Dc, row0, col0, acc);

  const int lane = threadIdx.x & 63, wave = threadIdx.x >> 6;
  const int wm = (wave >> 1) * 64, wn = (wave & 1) * 64;
  const int cr = (lane >> 4) * 4, cc = lane & 15;
  const float* bias = (z == 0) ? biasq : (z == 1) ? biask : biasv;
#pragma unroll
  for (int j = 0; j < 4; ++j) {
    const int gc = col0 + wn + j * 16 + cc;
    const float bb = bias[gc];
#pragma unroll
    for (int i = 0; i < 4; ++i) {
      const int gr = row0 + wm + i * 16 + cr;
      f32x4 v = acc[i][j];
      if (z < 2) {
        u16* dst = QKout + (size_t)z * NTOK * Dc + (size_t)gr * Dc + gc;
#pragma unroll
        for (int r = 0; r < 4; ++r) dst[(size_t)r * Dc] = f2b(v[r] + bb);
      } else {
        const int b = gr >> 10, t = gr & (Sc - 1);  // t multiple of 4
        ushort4 o = make_ushort4(f2b(v[0] + bb), f2b(v[1] + bb), f2b(v[2] + bb), f2b(v[3] + bb));
        *reinterpret_cast<ushort4*>(Vt + (size_t)b * Dc * Sc + (size_t)gc * Sc + t) = o;
      }
    }
  }
}

// ---------------- scores GEMM (64x128) + entropy epilogue -> combined fp32 ----------------
__global__ __launch_bounds__(256, 4) void gemm_scores(const u16* __restrict__ Qb,
                                                      const u16* __restrict__ Kb,
                                                      const float* __restrict__ agg,
                                                      float* __restrict__ comb) {
  int bx, by, z; xcd_map(bx, by, z);
  const int row0 = bx * 64, col0 = by * 128;
  const u16* A  = Qb + (size_t)z * Sc * Dc;
  const u16* Bt = Kb + (size_t)z * Sc * Dc;
  f32x4 acc[2][4] = {};
  gemm2<64>(A, Bt, Dc, row0, col0, acc);

  const int lane = threadIdx.x & 63, wave = threadIdx.x >> 6;
  const int wm = (wave >> 1) * 32, wn = (wave & 1) * 64;
  const int cr = (lane >> 4) * 4, cc = lane & 15;
  const float* qA = agg + (size_t)z * Sc;
  const float* qS = agg + NTOK + (size_t)z * Sc;
  const float* kA = agg + 2 * NTOK + (size_t)z * Sc;
  const float* kS = agg + 3 * NTOK + (size_t)z * Sc;
  float* C = comb + (size_t)z * Sc * Sc;
#pragma unroll
  for (int j = 0; j < 4; ++j) {
    const int gc = col0 + wn + j * 16 + cc;
    const float kAv = kA[gc], kSv = kS[gc];
#pragma unroll
    for (int i = 0; i < 2; ++i) {
      const int gr = row0 + wm + i * 16 + cr;
      f32x4 v = acc[i][j];
#pragma unroll
      for (int r = 0; r < 4; ++r) {
        const int s = gr + r;
        const float Z = qA[s] + kAv;
        const float ent = __logf(Z) - (qS[s] + kSv) / Z;
        C[(size_t)s * Sc + gc] = CSCALE * v[r] + ESCALE * ent;
      }
    }
  }
}

// ---------------- row softmax: comb -> attn fp32 (d_out) + attn bf16 (ws) ----------------
__global__ __launch_bounds__(256) void softmax_row(const float* __restrict__ comb,
                                                   float* __restrict__ attn_f,
                                                   u16* __restrict__ attn_b) {
  const int row = blockIdx.x;
  const int t = threadIdx.x;
  const float* src = comb + (size_t)row * Sc;
  float4 v = reinterpret_cast<const float4*>(src)[t];
  float m = fmaxf(fmaxf(v.x, v.y), fmaxf(v.z, v.w));
#pragma unroll
  for (int off = 1; off < 64; off <<= 1) m = fmaxf(m, __shfl_xor(m, off));
  __shared__ float red[8];
  if ((t & 63) == 0) red[t >> 6] = m;
  __syncthreads();
  m = fmaxf(fmaxf(red[0], red[1]), fmaxf(red[2], red[3]));
  float e0 = __expf(v.x - m), e1 = __expf(v.y - m), e2 = __expf(v.z - m), e3 = __expf(v.w - m);
  float s = e0 + e1 + e2 + e3;
#pragma unroll
  for (int off = 1; off < 64; off <<= 1) s += __shfl_xor(s, off);
  if ((t & 63) == 0) red[4 + (t >> 6)] = s;
  __syncthreads();
  s = red[4] + red[5] + red[6] + red[7];
  const float inv = 1.f / s;
  float4 o = make_float4(e0 * inv, e1 * inv, e2 * inv, e3 * inv);
  reinterpret_cast<float4*>(attn_f + (size_t)row * Sc)[t] = o;
  ushort4 ob = make_ushort4(f2b(o.x), f2b(o.y), f2b(o.z), f2b(o.w));
  reinterpret_cast<ushort4*>(attn_b + (size_t)row * Sc)[t] = ob;
}

// ---------------- attended = attn @ V  (64x128, Bt = Vt[b][d][t]) ----------------
__global__ __launch_bounds__(256, 4) void gemm_av(const u16* __restrict__ attnb,
                                                  const u16* __restrict__ Vt,
                                                  u16* __restrict__ att) {
  int bx, by, z; xcd_map(bx, by, z);
  const int row0 = bx * 64, col0 = by * 128;
  const u16* A  = attnb + (size_t)z * Sc * Sc;
  const u16* Bt = Vt + (size_t)z * Dc * Sc;
  f32x4 acc[2][4] = {};
  gemm2<64>(A, Bt, Sc, row0, col0, acc);

  const int lane = threadIdx.x & 63, wave = threadIdx.x >> 6;
  const int wm = (wave >> 1) * 32, wn = (wave & 1) * 64;
  const int cr = (lane >> 4) * 4, cc = lane & 15;
  u16* C = att + (size_t)z * Sc * Dc;
#pragma unroll
  for (int j = 0; j < 4; ++j) {
    const int gc = col0 + wn + j * 16 + cc;
#pragma unroll
    for (int i = 0; i < 2; ++i) {
      const int gr = row0 + wm + i * 16 + cr;
      f32x4 v = acc[i][j];
#pragma unroll
      for (int r = 0; r < 4; ++r) C[(size_t)(gr + r) * Dc + gc] = f2b(v[r]);
    }
  }
}

// ---------------- output = attended @ Wo^T + bo -> fp32 d_out (64x128) ----------------
__global__ __launch_bounds__(256, 4) void gemm_out(const u16* __restrict__ att,
                                                   const u16* __restrict__ Wob,
                                                   const float* __restrict__ bo,
                                                   float* __restrict__ out) {
  int bx, by, bz; xcd_map(bx, by, bz);
  const int row0 = bx * 64, col0 = by * 128;
  f32x4 acc[2][4] = {};
  gemm2<64>(att, Wob, Dc, row0, col0, acc);

  const int lane = threadIdx.x & 63, wave = threadIdx.x >> 6;
  const int wm = (wave >> 1) * 32, wn = (wave & 1) * 64;
  const int cr = (lane >> 4) * 4, cc = lane & 15;
#pragma unroll
  for (int j = 0; j < 4; ++j) {
    const int gc = col0 + wn + j * 16 + cc;
    const float bb = bo[gc];
#pragma unroll
    for (int i = 0; i < 2; ++i) {
      const int gr = row0 + wm + i * 16 + cr;
      f32x4 v = acc[i][j];
#pragma unroll
      for (int r = 0; r < 4; ++r) out[(size_t)(gr + r) * Dc + gc] = v[r] + bb;
    }
  }
}

extern "C" void kernel_launch(void* const* d_in, const int* in_sizes, int n_in,
                              void* d_out, int out_size, void* d_ws, size_t ws_size,
                              hipStream_t stream) {
  const float* query = (const float*)d_in[0];
  const float* key   = (const float*)d_in[1];
  const float* value = (const float*)d_in[2];
  const float* Wq = (const float*)d_in[3];
  const float* bq = (const float*)d_in[4];
  const float* Wk = (const float*)d_in[5];
  const float* bk = (const float*)d_in[6];
  const float* Wv = (const float*)d_in[7];
  const float* bv = (const float*)d_in[8];
  const float* Wo = (const float*)d_in[9];
  const float* bo = (const float*)d_in[10];

  float* out    = (float*)d_out;                    // [B,S,D]
  float* attn_f = out + (size_t)NTOK * Dc;          // [B,S,S]

  char* w = (char*)d_ws;
  const size_t MB = 1ull << 20;
  // Lifetime-overlaid layout (~56 MB):
  //  [0,24)MB : qx,kx,vx; then comb fp32 [0,16) + attnb [16,24)
  //  [24,40)MB: Qb,Kb; then attended overlays [24,32)
  //  [40,48)MB: Vt
  //  [48,56)MB: Wq,Wk,Wv,Wo bf16
  //  [56,..)  : entropy aggregates (64 KB)
  u16* qx = (u16*)(w);
  u16* kx = (u16*)(w + 8 * MB);
  u16* vx = (u16*)(w + 16 * MB);
  float* comb = (float*)(w);
  u16* attnb  = (u16*)(w + 16 * MB);
  u16* Qb = (u16*)(w + 24 * MB);            // Kb = Qb + NTOK*Dc
  u16* attended = (u16*)(w + 24 * MB);
  u16* Vt = (u16*)(w + 40 * MB);
  u16* Wb = (u16*)(w + 48 * MB);            // wq,wk,wv,wo contiguous (2MB each)
  float* agg = (float*)(w + 56 * MB);

  const int n4tok = NTOK * Dc / 4;  // 1048576
  const int n4w   = Dc * Dc / 4;    // 262144

  // 1. casts
  cast_bf16<<<n4tok / 256, 256, 0, stream>>>(query, qx, n4tok);
  cast_bf16<<<n4tok / 256, 256, 0, stream>>>(key,   kx, n4tok);
  cast_bf16<<<n4tok / 256, 256, 0, stream>>>(value, vx, n4tok);
  cast_bf16<<<n4w / 256, 256, 0, stream>>>(Wq, Wb + 0ull * Dc * Dc, n4w);
  cast_bf16<<<n4w / 256, 256, 0, stream>>>(Wk, Wb + 1ull * Dc * Dc, n4w);
  cast_bf16<<<n4w / 256, 256, 0, stream>>>(Wv, Wb + 2ull * Dc * Dc, n4w);
  cast_bf16<<<n4w / 256, 256, 0, stream>>>(Wo, Wb + 3ull * Dc * Dc, n4w);

  // 2. entropy row aggregates
  ent_agg<<<(2 * NTOK) / 256, 256, 0, stream>>>(query, key, agg);

  // 3. Q/K/V projections (z=0,1,2), V written transposed. 768 blocks, 3/CU.
  gemm_proj<<<dim3(32, 8, 3), 256, 0, stream>>>(qx, Wb, bq, bk, bv, Qb, Vt);

  // 4. combined scores. 512 blocks, 2/CU.
  gemm_scores<<<dim3(16, 8, 4), 256, 0, stream>>>(Qb, Qb + (size_t)NTOK * Dc, agg, comb);

  // 5. softmax rows -> attn (fp32 to d_out, bf16 to ws)
  softmax_row<<<NTOK, 256, 0, stream>>>(comb, attn_f, attnb);

  // 6. attended = attn @ V. 512 blocks.
  gemm_av<<<dim3(16, 8, 4), 256, 0, stream>>>(attnb, Vt, attended);

  // 7. output = attended @ Wo^T + bo. 512 blocks.
  gemm_out<<<dim3(64, 8, 1), 256, 0, stream>>>(attended, Wb + 3ull * Dc * Dc, bo, out);

  (void)in_sizes; (void)n_in; (void)out_size; (void)ws_size;
}

// Round 5
// 233.605 us; speedup vs baseline: 1.2928x; 1.0517x over previous
//
#include <hip/hip_runtime.h>

// QuantumAttentionMechanism on MI355X (gfx950)
// B=4, S=1024, D=1024, H=16, NQ=8, HEAD_DIM=64, ALPHA=0.7
//
// Math simplifications (exact up to fp rounding):
//   classical.mean(h) = (Q . K over full D) / (H*sqrt(HEAD_DIM)) = dot/128
//   entropy(i,j) = log(Z) - (Sa_i + Sb_j)/Z,  Z = A_i + B_j  (per-row aggregates, NQ=8)
//   attended = attn @ V (full D), output = attended @ Wo^T + bo.
//
// GEMM core (round 5): depth-2 counted pipeline (T4). 3 LDS buffers, BK=32,
// 4 waves. Per K-step: stage(t+2) -> ds_read+MFMA(t) -> vmcnt(NL) [t+1 complete,
// t+2 in flight ACROSS the barrier] -> s_barrier. Tail uses vmcnt(0).
// T2 involution swizzle slot^=(row>>1)&3 both-sides (bank conflicts = 0, r3/r4).
// Bijective XCD swizzle (T1). Casts merged into one kernel.

typedef float f32x4 __attribute__((ext_vector_type(4)));
typedef short s16x8 __attribute__((ext_vector_type(8)));
typedef unsigned short u16;

#define Bc 4
#define Sc 1024
#define Dc 1024
#define NTOK (Bc * Sc)          // 4096
#define CSCALE (0.7f / 128.0f)  // ALPHA / (H*sqrt(HEAD_DIM))
#define ESCALE 0.3f             // 1-ALPHA

typedef void __attribute__((address_space(1))) as1_void;
typedef void __attribute__((address_space(3))) as3_void;

__device__ __forceinline__ u16 f2b(float f) {  // fp32 -> bf16 RNE
  union { float f; unsigned u; } v; v.f = f;
  unsigned r = v.u + 0x7fffu + ((v.u >> 16) & 1u);
  return (u16)(r >> 16);
}

__device__ __forceinline__ void xcd_map(int& bx, int& by, int& bz) {
  const int gx = gridDim.x, gy = gridDim.y;
  const int nwg = gx * gy * gridDim.z;        // all grids here are %8 == 0
  const int lid = blockIdx.x + gx * (blockIdx.y + gy * blockIdx.z);
  const int cpx = nwg >> 3;
  const int s = (lid & 7) * cpx + (lid >> 3);
  bx = s % gx; const int r = s / gx; by = r % gy; bz = r / gy;
}

// ---------------- merged fp32 -> bf16 casts (q,k,v,Wq,Wk,Wv,Wo) ----------------
__global__ __launch_bounds__(256) void cast_all(const float* __restrict__ q,
                                                const float* __restrict__ k,
                                                const float* __restrict__ v,
                                                const float* __restrict__ wq,
                                                const float* __restrict__ wk,
                                                const float* __restrict__ wv,
                                                const float* __restrict__ wo,
                                                u16* __restrict__ qx, u16* __restrict__ kx,
                                                u16* __restrict__ vx, u16* __restrict__ Wb) {
  const int i = blockIdx.x * 256 + threadIdx.x;  // float4 index, 4.19M total
  const float* src; u16* dst; int off;
  if (i < 3145728) {                      // 3 x 1048576 (token tensors)
    const int t = i >> 20; off = i & 1048575;
    src = (t == 0) ? q : (t == 1) ? k : v;
    dst = (t == 0) ? qx : (t == 1) ? kx : vx;
  } else {                                // 4 x 262144 (weights)
    const int j = i - 3145728; const int t = j >> 18; off = j & 262143;
    src = (t == 0) ? wq : (t == 1) ? wk : (t == 2) ? wv : wo;
    dst = Wb + (size_t)t * Dc * Dc;
  }
  float4 vv = reinterpret_cast<const float4*>(src)[off];
  reinterpret_cast<ushort4*>(dst)[off] =
      make_ushort4(f2b(vv.x), f2b(vv.y), f2b(vv.z), f2b(vv.w));
}

// ---------------- per-row entropy aggregates ----------------
__global__ __launch_bounds__(256) void ent_agg(const float* __restrict__ q,
                                               const float* __restrict__ k,
                                               float* __restrict__ agg) {
  int r = blockIdx.x * 256 + threadIdx.x;
  if (r >= 2 * NTOK) return;
  const float* src = (r < NTOK) ? (q + (size_t)r * Dc) : (k + (size_t)(r - NTOK) * Dc);
  float A = 0.f, Sv = 0.f;
#pragma unroll
  for (int m = 0; m < 8; ++m) {
    float e = tanhf(src[m]);
    float a = __expf(e);
    A += a; Sv += a * e;
  }
  if (r < NTOK) { agg[r] = A; agg[NTOK + r] = Sv; }
  else          { agg[NTOK + r] = A; agg[3 * NTOK + (r - NTOK)] = Sv; }
}

// ------------- depth-2 counted-pipeline GEMM core: C[BM x 128], K=1024 -------------
// 256 threads, 4 waves 2x2 (wave tile BM/2 x 64). NL = global_load_lds per stage.
template<int BM, int NL>
__device__ __forceinline__ void gemm3(const u16* __restrict__ A, const u16* __restrict__ Bt,
                                      int row0, int col0, f32x4 (*acc)[4]) {
  constexpr int MR = BM / 32;          // 128 -> 4, 64 -> 2
  constexpr int ASZ = BM * 32;
  constexpr int BSZ = 128 * 32;
  constexpr int K = 1024, nk = 32;
  __shared__ __align__(16) u16 LA[3 * ASZ];
  __shared__ __align__(16) u16 LB[3 * BSZ];
  const int tid = threadIdx.x;
  const int lane = tid & 63, wave = tid >> 6;
  const int wr = wave >> 1, wc = wave & 1;
  const int fr = lane & 15, g = lane >> 4;

  // stage addressing: LDS linear (row = tid>>2, slot = tid&3), source pre-swizzled
  const int rA0 = tid >> 2;
  const int slA0 = (tid & 3) ^ ((rA0 >> 1) & 3);
  const u16* gA0 = A + (size_t)(row0 + rA0) * K + slA0 * 8;
  const u16* gA1 = nullptr;
  if constexpr (BM == 128) {
    const int rA1 = rA0 + 64;
    const int slA1 = (tid & 3) ^ ((rA1 >> 1) & 3);
    gA1 = A + (size_t)(row0 + rA1) * K + slA1 * 8;
  }
  const int rB1 = rA0 + 64;
  const int slB1 = (tid & 3) ^ ((rB1 >> 1) & 3);
  const u16* gB0 = Bt + (size_t)(col0 + rA0) * K + slA0 * 8;
  const u16* gB1 = Bt + (size_t)(col0 + rB1) * K + slB1 * 8;

  // swizzled ds_read element-offsets
  int aoff[MR], boff[4];
#pragma unroll
  for (int i = 0; i < MR; ++i) {
    const int row = wr * (MR * 16) + i * 16 + fr;
    aoff[i] = row * 32 + ((g ^ ((row >> 1) & 3)) << 3);
  }
#pragma unroll
  for (int j = 0; j < 4; ++j) {
    const int row = wc * 64 + j * 16 + fr;
    boff[j] = row * 32 + ((g ^ ((row >> 1) & 3)) << 3);
  }

  auto stage = [&](int aofs, int bofs, int kt) {
    const int ko = kt * 32;
    __builtin_amdgcn_global_load_lds((const as1_void*)(gA0 + ko),
                                     (as3_void*)(&LA[aofs + tid * 8]), 16, 0, 0);
    if constexpr (BM == 128)
      __builtin_amdgcn_global_load_lds((const as1_void*)(gA1 + ko),
                                       (as3_void*)(&LA[aofs + (256 + tid) * 8]), 16, 0, 0);
    __builtin_amdgcn_global_load_lds((const as1_void*)(gB0 + ko),
                                     (as3_void*)(&LB[bofs + tid * 8]), 16, 0, 0);
    __builtin_amdgcn_global_load_lds((const as1_void*)(gB1 + ko),
                                     (as3_void*)(&LB[bofs + (256 + tid) * 8]), 16, 0, 0);
  };

  // prologue: stages for t0, t1 in flight; wait for t0 only (vmcnt(NL)).
  stage(0, 0, 0);
  stage(ASZ, BSZ, 1);
  if constexpr (NL == 4) asm volatile("s_waitcnt vmcnt(4)" ::: "memory");
  else                   asm volatile("s_waitcnt vmcnt(3)" ::: "memory");
  __builtin_amdgcn_s_barrier();
  __builtin_amdgcn_sched_barrier(0);

  int a0 = 0, a1 = ASZ, a2 = 2 * ASZ;   // cur / next / stage-target (A)
  int b0 = 0, b1 = BSZ, b2 = 2 * BSZ;
  for (int kt = 0; kt < nk; ++kt) {
    if (kt + 2 < nk) stage(a2, b2, kt + 2);
    s16x8 af[MR], bf[4];
#pragma unroll
    for (int i = 0; i < MR; ++i) af[i] = *reinterpret_cast<const s16x8*>(&LA[a0 + aoff[i]]);
#pragma unroll
    for (int j = 0; j < 4; ++j) bf[j] = *reinterpret_cast<const s16x8*>(&LB[b0 + boff[j]]);
#pragma unroll
    for (int i = 0; i < MR; ++i)
#pragma unroll
      for (int j = 0; j < 4; ++j)
        acc[i][j] = __builtin_amdgcn_mfma_f32_16x16x32_bf16(af[i], bf[j], acc[i][j], 0, 0, 0);
    if (kt + 1 < nk) {
      if (kt + 2 < nk) {  // t+1 complete; t+2's NL loads stay in flight
        if constexpr (NL == 4) asm volatile("s_waitcnt vmcnt(4)" ::: "memory");
        else                   asm volatile("s_waitcnt vmcnt(3)" ::: "memory");
      } else {
        asm volatile("s_waitcnt vmcnt(0)" ::: "memory");
      }
      __builtin_amdgcn_s_barrier();
      __builtin_amdgcn_sched_barrier(0);
    }
    int t = a0; a0 = a1; a1 = a2; a2 = t;
    t = b0; b0 = b1; b1 = b2; b2 = t;
  }
}

// ---------------- QKV projections (z=0:Q, 1:K, 2:V-transposed), 128x128 ----------------
__global__ __launch_bounds__(256, 3) void gemm_proj(const u16* __restrict__ Xall,
                                                    const u16* __restrict__ Wall,
                                                    const float* __restrict__ biasq,
                                                    const float* __restrict__ biask,
                                                    const float* __restrict__ biasv,
                                                    u16* __restrict__ QKout,
                                                    u16* __restrict__ Vt) {
  int bx, by, z; xcd_map(bx, by, z);
  const int row0 = bx * 128, col0 = by * 128;
  const u16* A  = Xall + (size_t)z * NTOK * Dc;
  const u16* Bt = Wall + (size_t)z * Dc * Dc;
  f32x4 acc[4][4] = {};
  gemm3<128, 4>(A, Bt, row0, col0, acc);

  const int lane = threadIdx.x & 63, wave = threadIdx.x >> 6;
  const int wm = (wave >> 1) * 64, wn = (wave & 1) * 64;
  const int cr = (lane >> 4) * 4, cc = lane & 15;
  const float* bias = (z == 0) ? biasq : (z == 1) ? biask : biasv;
#pragma unroll
  for (int j = 0; j < 4; ++j) {
    const int gc = col0 + wn + j * 16 + cc;
    const float bb = bias[gc];
#pragma unroll
    for (int i = 0; i < 4; ++i) {
      const int gr = row0 + wm + i * 16 + cr;
      f32x4 v = acc[i][j];
      if (z < 2) {
        u16* dst = QKout + (size_t)z * NTOK * Dc + (size_t)gr * Dc + gc;
#pragma unroll
        for (int r = 0; r < 4; ++r) dst[(size_t)r * Dc] = f2b(v[r] + bb);
      } else {
        const int b = gr >> 10, t = gr & (Sc - 1);  // t multiple of 4
        ushort4 o = make_ushort4(f2b(v[0] + bb), f2b(v[1] + bb), f2b(v[2] + bb), f2b(v[3] + bb));
        *reinterpret_cast<ushort4*>(Vt + (size_t)b * Dc * Sc + (size_t)gc * Sc + t) = o;
      }
    }
  }
}

// ---------------- scores GEMM (64x128) + entropy epilogue -> combined fp32 ----------------
__global__ __launch_bounds__(256, 4) void gemm_scores(const u16* __restrict__ Qb,
                                                      const u16* __restrict__ Kb,
                                                      const float* __restrict__ agg,
                                                      float* __restrict__ comb) {
  int bx, by, z; xcd_map(bx, by, z);
  const int row0 = bx * 64, col0 = by * 128;
  const u16* A  = Qb + (size_t)z * Sc * Dc;
  const u16* Bt = Kb + (size_t)z * Sc * Dc;
  f32x4 acc[2][4] = {};
  gemm3<64, 3>(A, Bt, row0, col0, acc);

  const int lane = threadIdx.x & 63, wave = threadIdx.x >> 6;
  const int wm = (wave >> 1) * 32, wn = (wave & 1) * 64;
  const int cr = (lane >> 4) * 4, cc = lane & 15;
  const float* qA = agg + (size_t)z * Sc;
  const float* qS = agg + NTOK + (size_t)z * Sc;
  const float* kA = agg + 2 * NTOK + (size_t)z * Sc;
  const float* kS = agg + 3 * NTOK + (size_t)z * Sc;
  float* C = comb + (size_t)z * Sc * Sc;
#pragma unroll
  for (int j = 0; j < 4; ++j) {
    const int gc = col0 + wn + j * 16 + cc;
    const float kAv = kA[gc], kSv = kS[gc];
#pragma unroll
    for (int i = 0; i < 2; ++i) {
      const int gr = row0 + wm + i * 16 + cr;
      f32x4 v = acc[i][j];
#pragma unroll
      for (int r = 0; r < 4; ++r) {
        const int s = gr + r;
        const float Z = qA[s] + kAv;
        const float ent = __logf(Z) - (qS[s] + kSv) / Z;
        C[(size_t)s * Sc + gc] = CSCALE * v[r] + ESCALE * ent;
      }
    }
  }
}

// ---------------- row softmax: comb -> attn fp32 (d_out) + attn bf16 (ws) ----------------
__global__ __launch_bounds__(256) void softmax_row(const float* __restrict__ comb,
                                                   float* __restrict__ attn_f,
                                                   u16* __restrict__ attn_b) {
  const int row = blockIdx.x;
  const int t = threadIdx.x;
  const float* src = comb + (size_t)row * Sc;
  float4 v = reinterpret_cast<const float4*>(src)[t];
  float m = fmaxf(fmaxf(v.x, v.y), fmaxf(v.z, v.w));
#pragma unroll
  for (int off = 1; off < 64; off <<= 1) m = fmaxf(m, __shfl_xor(m, off));
  __shared__ float red[8];
  if ((t & 63) == 0) red[t >> 6] = m;
  __syncthreads();
  m = fmaxf(fmaxf(red[0], red[1]), fmaxf(red[2], red[3]));
  float e0 = __expf(v.x - m), e1 = __expf(v.y - m), e2 = __expf(v.z - m), e3 = __expf(v.w - m);
  float s = e0 + e1 + e2 + e3;
#pragma unroll
  for (int off = 1; off < 64; off <<= 1) s += __shfl_xor(s, off);
  if ((t & 63) == 0) red[4 + (t >> 6)] = s;
  __syncthreads();
  s = red[4] + red[5] + red[6] + red[7];
  const float inv = 1.f / s;
  float4 o = make_float4(e0 * inv, e1 * inv, e2 * inv, e3 * inv);
  reinterpret_cast<float4*>(attn_f + (size_t)row * Sc)[t] = o;
  ushort4 ob = make_ushort4(f2b(o.x), f2b(o.y), f2b(o.z), f2b(o.w));
  reinterpret_cast<ushort4*>(attn_b + (size_t)row * Sc)[t] = ob;
}

// ---------------- attended = attn @ V  (64x128, Bt = Vt[b][d][t]) ----------------
__global__ __launch_bounds__(256, 4) void gemm_av(const u16* __restrict__ attnb,
                                                  const u16* __restrict__ Vt,
                                                  u16* __restrict__ att) {
  int bx, by, z; xcd_map(bx, by, z);
  const int row0 = bx * 64, col0 = by * 128;
  const u16* A  = attnb + (size_t)z * Sc * Sc;
  const u16* Bt = Vt + (size_t)z * Dc * Sc;
  f32x4 acc[2][4] = {};
  gemm3<64, 3>(A, Bt, row0, col0, acc);

  const int lane = threadIdx.x & 63, wave = threadIdx.x >> 6;
  const int wm = (wave >> 1) * 32, wn = (wave & 1) * 64;
  const int cr = (lane >> 4) * 4, cc = lane & 15;
  u16* C = att + (size_t)z * Sc * Dc;
#pragma unroll
  for (int j = 0; j < 4; ++j) {
    const int gc = col0 + wn + j * 16 + cc;
#pragma unroll
    for (int i = 0; i < 2; ++i) {
      const int gr = row0 + wm + i * 16 + cr;
      f32x4 v = acc[i][j];
#pragma unroll
      for (int r = 0; r < 4; ++r) C[(size_t)(gr + r) * Dc + gc] = f2b(v[r]);
    }
  }
}

// ---------------- output = attended @ Wo^T + bo -> fp32 d_out (64x128) ----------------
__global__ __launch_bounds__(256, 4) void gemm_out(const u16* __restrict__ att,
                                                   const u16* __restrict__ Wob,
                                                   const float* __restrict__ bo,
                                                   float* __restrict__ out) {
  int bx, by, bz; xcd_map(bx, by, bz);
  const int row0 = bx * 64, col0 = by * 128;
  f32x4 acc[2][4] = {};
  gemm3<64, 3>(att, Wob, row0, col0, acc);

  const int lane = threadIdx.x & 63, wave = threadIdx.x >> 6;
  const int wm = (wave >> 1) * 32, wn = (wave & 1) * 64;
  const int cr = (lane >> 4) * 4, cc = lane & 15;
#pragma unroll
  for (int j = 0; j < 4; ++j) {
    const int gc = col0 + wn + j * 16 + cc;
    const float bb = bo[gc];
#pragma unroll
    for (int i = 0; i < 2; ++i) {
      const int gr = row0 + wm + i * 16 + cr;
      f32x4 v = acc[i][j];
#pragma unroll
      for (int r = 0; r < 4; ++r) out[(size_t)(gr + r) * Dc + gc] = v[r] + bb;
    }
  }
}

extern "C" void kernel_launch(void* const* d_in, const int* in_sizes, int n_in,
                              void* d_out, int out_size, void* d_ws, size_t ws_size,
                              hipStream_t stream) {
  const float* query = (const float*)d_in[0];
  const float* key   = (const float*)d_in[1];
  const float* value = (const float*)d_in[2];
  const float* Wq = (const float*)d_in[3];
  const float* bq = (const float*)d_in[4];
  const float* Wk = (const float*)d_in[5];
  const float* bk = (const float*)d_in[6];
  const float* Wv = (const float*)d_in[7];
  const float* bv = (const float*)d_in[8];
  const float* Wo = (const float*)d_in[9];
  const float* bo = (const float*)d_in[10];

  float* out    = (float*)d_out;                    // [B,S,D]
  float* attn_f = out + (size_t)NTOK * Dc;          // [B,S,S]

  char* w = (char*)d_ws;
  const size_t MB = 1ull << 20;
  // Lifetime-overlaid layout (~56 MB):
  //  [0,24)MB : qx,kx,vx; then comb fp32 [0,16) + attnb [16,24)
  //  [24,40)MB: Qb,Kb; then attended overlays [24,32)
  //  [40,48)MB: Vt
  //  [48,56)MB: Wq,Wk,Wv,Wo bf16
  //  [56,..)  : entropy aggregates (64 KB)
  u16* qx = (u16*)(w);
  u16* kx = (u16*)(w + 8 * MB);
  u16* vx = (u16*)(w + 16 * MB);
  float* comb = (float*)(w);
  u16* attnb  = (u16*)(w + 16 * MB);
  u16* Qb = (u16*)(w + 24 * MB);            // Kb = Qb + NTOK*Dc
  u16* attended = (u16*)(w + 24 * MB);
  u16* Vt = (u16*)(w + 40 * MB);
  u16* Wb = (u16*)(w + 48 * MB);            // wq,wk,wv,wo contiguous (2MB each)
  float* agg = (float*)(w + 56 * MB);

  // 1. merged casts (3x16MB tokens + 4x4MB weights -> bf16)
  cast_all<<<16384, 256, 0, stream>>>(query, key, value, Wq, Wk, Wv, Wo, qx, kx, vx, Wb);

  // 2. entropy row aggregates
  ent_agg<<<(2 * NTOK) / 256, 256, 0, stream>>>(query, key, agg);

  // 3. Q/K/V projections (z=0,1,2), V written transposed. 768 blocks, 3/CU.
  gemm_proj<<<dim3(32, 8, 3), 256, 0, stream>>>(qx, Wb, bq, bk, bv, Qb, Vt);

  // 4. combined scores. 512 blocks, 2/CU.
  gemm_scores<<<dim3(16, 8, 4), 256, 0, stream>>>(Qb, Qb + (size_t)NTOK * Dc, agg, comb);

  // 5. softmax rows -> attn (fp32 to d_out, bf16 to ws)
  softmax_row<<<NTOK, 256, 0, stream>>>(comb, attn_f, attnb);

  // 6. attended = attn @ V. 512 blocks.
  gemm_av<<<dim3(16, 8, 4), 256, 0, stream>>>(attnb, Vt, attended);

  // 7. output = attended @ Wo^T + bo. 512 blocks.
  gemm_out<<<dim3(64, 8, 1), 256, 0, stream>>>(attended, Wb + 3ull * Dc * Dc, bo, out);

  (void)in_sizes; (void)n_in; (void)out_size; (void)ws_size;
}

// Round 7
// 226.135 us; speedup vs baseline: 1.3355x; 1.0330x over previous
//
#include <hip/hip_runtime.h>

// QuantumAttentionMechanism on MI355X (gfx950)
// B=4, S=1024, D=1024, H=16, NQ=8, HEAD_DIM=64, ALPHA=0.7
//
// Math simplifications (exact up to fp rounding):
//   classical.mean(h) = (Q . K over full D) / (H*sqrt(HEAD_DIM)) = dot/128
//   entropy(i,j) = log(Z) - (Sa_i + Sb_j)/Z,  Z = A_i + B_j  (per-row aggregates, NQ=8)
//   attended = attn @ V (full D), output = attended @ Wo^T + bo.
//
// Round 7 = Round 6 with the Vt transpose epilogue fixed (m<8, was m<4: only
// half the Vt tile was written -> absmax 9.1e-2). 512-thread / 8-wave GEMM
// blocks, depth-2 counted-vmcnt pipeline (3 LDS buffers, BK=32), T2 involution
// swizzle (conflicts=0), bijective XCD swizzle by-fastest decode, LDS-transpose
// epilogue for coalesced Vt writes.

typedef float f32x4 __attribute__((ext_vector_type(4)));
typedef short s16x8 __attribute__((ext_vector_type(8)));
typedef unsigned short u16;

#define Bc 4
#define Sc 1024
#define Dc 1024
#define NTOK (Bc * Sc)          // 4096
#define CSCALE (0.7f / 128.0f)  // ALPHA / (H*sqrt(HEAD_DIM))
#define ESCALE 0.3f             // 1-ALPHA

typedef void __attribute__((address_space(1))) as1_void;
typedef void __attribute__((address_space(3))) as3_void;

__device__ __forceinline__ u16 f2b(float f) {  // fp32 -> bf16 RNE
  union { float f; unsigned u; } v; v.f = f;
  unsigned r = v.u + 0x7fffu + ((v.u >> 16) & 1u);
  return (u16)(r >> 16);
}

// XCD swizzle: chunk the grid across 8 XCDs; decode by-fastest so consecutive
// blocks within an XCD share the same A-row panel (L2 reuse).
__device__ __forceinline__ void xcd_map(int& bx, int& by, int& bz) {
  const int gx = gridDim.x, gy = gridDim.y;
  const int nwg = gx * gy * gridDim.z;        // all grids here are %8 == 0
  const int lid = blockIdx.x + gx * (blockIdx.y + gy * blockIdx.z);
  const int cpx = nwg >> 3;
  const int s = (lid & 7) * cpx + (lid >> 3);
  by = s % gy; const int r = s / gy; bx = r % gx; bz = r / gx;
}

// ---------------- merged fp32 -> bf16 casts (q,k,v,Wq,Wk,Wv,Wo) ----------------
__global__ __launch_bounds__(256) void cast_all(const float* __restrict__ q,
                                                const float* __restrict__ k,
                                                const float* __restrict__ v,
                                                const float* __restrict__ wq,
                                                const float* __restrict__ wk,
                                                const float* __restrict__ wv,
                                                const float* __restrict__ wo,
                                                u16* __restrict__ qx, u16* __restrict__ kx,
                                                u16* __restrict__ vx, u16* __restrict__ Wb) {
  const int i = blockIdx.x * 256 + threadIdx.x;  // float4 index
  const float* src; u16* dst; int off;
  if (i < 3145728) {                      // 3 x 1048576 (token tensors)
    const int t = i >> 20; off = i & 1048575;
    src = (t == 0) ? q : (t == 1) ? k : v;
    dst = (t == 0) ? qx : (t == 1) ? kx : vx;
  } else {                                // 4 x 262144 (weights)
    const int j = i - 3145728; const int t = j >> 18; off = j & 262143;
    src = (t == 0) ? wq : (t == 1) ? wk : (t == 2) ? wv : wo;
    dst = Wb + (size_t)t * Dc * Dc;
  }
  float4 vv = reinterpret_cast<const float4*>(src)[off];
  reinterpret_cast<ushort4*>(dst)[off] =
      make_ushort4(f2b(vv.x), f2b(vv.y), f2b(vv.z), f2b(vv.w));
}

// ---------------- per-row entropy aggregates ----------------
__global__ __launch_bounds__(256) void ent_agg(const float* __restrict__ q,
                                               const float* __restrict__ k,
                                               float* __restrict__ agg) {
  int r = blockIdx.x * 256 + threadIdx.x;
  if (r >= 2 * NTOK) return;
  const float* src = (r < NTOK) ? (q + (size_t)r * Dc) : (k + (size_t)(r - NTOK) * Dc);
  float A = 0.f, Sv = 0.f;
#pragma unroll
  for (int m = 0; m < 8; ++m) {
    float e = tanhf(src[m]);
    float a = __expf(e);
    A += a; Sv += a * e;
  }
  if (r < NTOK) { agg[r] = A; agg[NTOK + r] = Sv; }
  else          { agg[NTOK + r] = A; agg[3 * NTOK + (r - NTOK)] = Sv; }
}

// ------ 8-wave depth-2 counted-pipeline GEMM core: C[BM x 128], K=1024 ------
// 512 threads, waves 2x4: wave tile (BM/2) x 32 -> acc[MR][2].
template<int BM>
__device__ __forceinline__ void gemm8(const u16* __restrict__ A, const u16* __restrict__ Bt,
                                      int row0, int col0, f32x4 (*acc)[2],
                                      u16* __restrict__ smem) {
  constexpr int MR = BM / 32;          // 128 -> 4, 64 -> 2
  constexpr int ASZ = BM * 32;         // u16 elems per A buffer
  constexpr int BSZ = 128 * 32;
  constexpr int K = 1024, nk = 32;
  u16* LA = smem;                      // 3 * ASZ
  u16* LB = smem + 3 * ASZ;            // 3 * BSZ
  const int tid = threadIdx.x;
  const int lane = tid & 63, wave = tid >> 6;
  const int wr = wave >> 2, wc = wave & 3;
  const int fr = lane & 15, g = lane >> 4;

  // staging: LDS linear chunk = tid (row tid>>2, slot tid&3), source pre-swizzled.
  const int rS = tid >> 2;
  const int slS = (tid & 3) ^ ((rS >> 1) & 3);
  const int rA = (BM == 128) ? rS : (rS & 63);   // clamp for unused hi threads
  const u16* gB = Bt + (size_t)(col0 + rS) * K + slS * 8;
  const u16* gA = A + (size_t)(row0 + rA) * K + slS * 8;

  // swizzled ds_read element-offsets
  int aoff[MR], boff[2];
#pragma unroll
  for (int i = 0; i < MR; ++i) {
    const int row = wr * (MR * 16) + i * 16 + fr;
    aoff[i] = row * 32 + ((g ^ ((row >> 1) & 3)) << 3);
  }
#pragma unroll
  for (int j = 0; j < 2; ++j) {
    const int row = wc * 32 + j * 16 + fr;
    boff[j] = row * 32 + ((g ^ ((row >> 1) & 3)) << 3);
  }

  auto stage = [&](int idx, int kt) {
    const int ko = kt * 32;
    if (BM == 128 || tid < 256)
      __builtin_amdgcn_global_load_lds((const as1_void*)(gA + ko),
                                       (as3_void*)(&LA[idx * ASZ + tid * 8]), 16, 0, 0);
    __builtin_amdgcn_global_load_lds((const as1_void*)(gB + ko),
                                     (as3_void*)(&LB[idx * BSZ + tid * 8]), 16, 0, 0);
  };
  auto wait_nl = [&]() {  // retire everything before the newest stage
    if constexpr (BM == 128) {
      asm volatile("s_waitcnt vmcnt(2)" ::: "memory");
    } else {
      if (tid < 256) asm volatile("s_waitcnt vmcnt(2)" ::: "memory");
      else           asm volatile("s_waitcnt vmcnt(1)" ::: "memory");
    }
  };

  stage(0, 0);
  stage(1, 1);
  wait_nl();
  __builtin_amdgcn_s_barrier();
  __builtin_amdgcn_sched_barrier(0);

  int c0 = 0, c1 = 1, c2 = 2;
  for (int kt = 0; kt < nk; ++kt) {
    if (kt + 2 < nk) stage(c2, kt + 2);
    const int ab = c0 * ASZ, bb = c0 * BSZ;
    s16x8 af[MR], bfr[2];
#pragma unroll
    for (int i = 0; i < MR; ++i) af[i] = *reinterpret_cast<const s16x8*>(&LA[ab + aoff[i]]);
#pragma unroll
    for (int j = 0; j < 2; ++j) bfr[j] = *reinterpret_cast<const s16x8*>(&LB[bb + boff[j]]);
#pragma unroll
    for (int i = 0; i < MR; ++i)
#pragma unroll
      for (int j = 0; j < 2; ++j)
        acc[i][j] = __builtin_amdgcn_mfma_f32_16x16x32_bf16(af[i], bfr[j], acc[i][j], 0, 0, 0);
    if (kt + 1 < nk) {
      if (kt + 2 < nk) wait_nl();
      else asm volatile("s_waitcnt vmcnt(0)" ::: "memory");
      __builtin_amdgcn_s_barrier();
      __builtin_amdgcn_sched_barrier(0);
    }
    int t = c0; c0 = c1; c1 = c2; c2 = t;
  }
}

// ---------------- QKV projections (z=0:Q, 1:K, 2:V-transposed), 128x128 ----------------
__global__ __launch_bounds__(512, 6) void gemm_proj(const u16* __restrict__ Xall,
                                                    const u16* __restrict__ Wall,
                                                    const float* __restrict__ biasq,
                                                    const float* __restrict__ biask,
                                                    const float* __restrict__ biasv,
                                                    u16* __restrict__ QKout,
                                                    u16* __restrict__ Vt) {
  __shared__ __align__(16) u16 smem[3 * (128 * 32) * 2];  // 48 KiB
  int bx, by, z; xcd_map(bx, by, z);
  const int row0 = bx * 128, col0 = by * 128;
  const u16* A  = Xall + (size_t)z * NTOK * Dc;
  const u16* Bt = Wall + (size_t)z * Dc * Dc;
  f32x4 acc[4][2] = {};
  gemm8<128>(A, Bt, row0, col0, acc, smem);

  const int tid = threadIdx.x;
  const int lane = tid & 63, wave = tid >> 6;
  const int wr = wave >> 2, wc = wave & 3;
  const int cr = (lane >> 4) * 4, cc = lane & 15;
  const float* bias = (z == 0) ? biasq : (z == 1) ? biask : biasv;
  if (z < 2) {
#pragma unroll
    for (int j = 0; j < 2; ++j) {
      const int gc = col0 + wc * 32 + j * 16 + cc;
      const float bb = bias[gc];
#pragma unroll
      for (int i = 0; i < 4; ++i) {
        const int gr = row0 + wr * 64 + i * 16 + cr;
        f32x4 v = acc[i][j];
        u16* dst = QKout + (size_t)z * NTOK * Dc + (size_t)gr * Dc + gc;
#pragma unroll
        for (int r = 0; r < 4; ++r) dst[(size_t)r * Dc] = f2b(v[r] + bb);
      }
    }
  } else {
    // transpose through LDS -> coalesced Vt writes
    __syncthreads();                 // all waves done with GEMM LDS reads
    u16* T = smem;                   // [128 d][132 t] bf16, padded stride
#pragma unroll
    for (int j = 0; j < 2; ++j) {
      const int lc = wc * 32 + j * 16 + cc;
      const float bb = bias[col0 + lc];
#pragma unroll
      for (int i = 0; i < 4; ++i) {
        const int lrb = wr * 64 + i * 16 + cr;
        f32x4 v = acc[i][j];
        ushort4 o = make_ushort4(f2b(v[0] + bb), f2b(v[1] + bb), f2b(v[2] + bb), f2b(v[3] + bb));
        *reinterpret_cast<ushort4*>(&T[lc * 132 + lrb]) = o;
      }
    }
    __syncthreads();
    const int d = tid >> 2, q = tid & 3;   // 4 threads per d-column
    const int b = row0 >> 10, t0 = row0 & (Sc - 1);
    u16* dst = Vt + (size_t)b * Dc * Sc + (size_t)(col0 + d) * Sc + t0 + q * 32;
#pragma unroll
    for (int m = 0; m < 8; ++m)  // 8 x ushort4 = 32 t-values (FIX: was 4)
      reinterpret_cast<ushort4*>(dst)[m] = *reinterpret_cast<const ushort4*>(&T[d * 132 + q * 32 + m * 4]);
  }
}

// ---------------- scores GEMM (64x128) + entropy epilogue -> combined fp32 ----------------
__global__ __launch_bounds__(512, 4) void gemm_scores(const u16* __restrict__ Qb,
                                                      const u16* __restrict__ Kb,
                                                      const float* __restrict__ agg,
                                                      float* __restrict__ comb) {
  __shared__ __align__(16) u16 smem[3 * (64 * 32) + 3 * (128 * 32)];  // 36 KiB
  int bx, by, z; xcd_map(bx, by, z);
  const int row0 = bx * 64, col0 = by * 128;
  const u16* A  = Qb + (size_t)z * Sc * Dc;
  const u16* Bt = Kb + (size_t)z * Sc * Dc;
  f32x4 acc[2][2] = {};
  gemm8<64>(A, Bt, row0, col0, acc, smem);

  const int lane = threadIdx.x & 63, wave = threadIdx.x >> 6;
  const int wr = wave >> 2, wc = wave & 3;
  const int cr = (lane >> 4) * 4, cc = lane & 15;
  const float* qA = agg + (size_t)z * Sc;
  const float* qS = agg + NTOK + (size_t)z * Sc;
  const float* kA = agg + 2 * NTOK + (size_t)z * Sc;
  const float* kS = agg + 3 * NTOK + (size_t)z * Sc;
  float* C = comb + (size_t)z * Sc * Sc;
#pragma unroll
  for (int j = 0; j < 2; ++j) {
    const int gc = col0 + wc * 32 + j * 16 + cc;
    const float kAv = kA[gc], kSv = kS[gc];
#pragma unroll
    for (int i = 0; i < 2; ++i) {
      const int gr = row0 + wr * 32 + i * 16 + cr;
      f32x4 v = acc[i][j];
#pragma unroll
      for (int r = 0; r < 4; ++r) {
        const int s = gr + r;
        const float Z = qA[s] + kAv;
        const float ent = __logf(Z) - (qS[s] + kSv) / Z;
        C[(size_t)s * Sc + gc] = CSCALE * v[r] + ESCALE * ent;
      }
    }
  }
}

// ---------------- row softmax: comb -> attn fp32 (d_out) + attn bf16 (ws) ----------------
__global__ __launch_bounds__(256) void softmax_row(const float* __restrict__ comb,
                                                   float* __restrict__ attn_f,
                                                   u16* __restrict__ attn_b) {
  const int row = blockIdx.x;
  const int t = threadIdx.x;
  const float* src = comb + (size_t)row * Sc;
  float4 v = reinterpret_cast<const float4*>(src)[t];
  float m = fmaxf(fmaxf(v.x, v.y), fmaxf(v.z, v.w));
#pragma unroll
  for (int off = 1; off < 64; off <<= 1) m = fmaxf(m, __shfl_xor(m, off));
  __shared__ float red[8];
  if ((t & 63) == 0) red[t >> 6] = m;
  __syncthreads();
  m = fmaxf(fmaxf(red[0], red[1]), fmaxf(red[2], red[3]));
  float e0 = __expf(v.x - m), e1 = __expf(v.y - m), e2 = __expf(v.z - m), e3 = __expf(v.w - m);
  float s = e0 + e1 + e2 + e3;
#pragma unroll
  for (int off = 1; off < 64; off <<= 1) s += __shfl_xor(s, off);
  if ((t & 63) == 0) red[4 + (t >> 6)] = s;
  __syncthreads();
  s = red[4] + red[5] + red[6] + red[7];
  const float inv = 1.f / s;
  float4 o = make_float4(e0 * inv, e1 * inv, e2 * inv, e3 * inv);
  reinterpret_cast<float4*>(attn_f + (size_t)row * Sc)[t] = o;
  ushort4 ob = make_ushort4(f2b(o.x), f2b(o.y), f2b(o.z), f2b(o.w));
  reinterpret_cast<ushort4*>(attn_b + (size_t)row * Sc)[t] = ob;
}

// ---------------- attended = attn @ V  (64x128, Bt = Vt[b][d][t]) ----------------
__global__ __launch_bounds__(512, 4) void gemm_av(const u16* __restrict__ attnb,
                                                  const u16* __restrict__ Vt,
                                                  u16* __restrict__ att) {
  __shared__ __align__(16) u16 smem[3 * (64 * 32) + 3 * (128 * 32)];
  int bx, by, z; xcd_map(bx, by, z);
  const int row0 = bx * 64, col0 = by * 128;
  const u16* A  = attnb + (size_t)z * Sc * Sc;
  const u16* Bt = Vt + (size_t)z * Dc * Sc;
  f32x4 acc[2][2] = {};
  gemm8<64>(A, Bt, row0, col0, acc, smem);

  const int lane = threadIdx.x & 63, wave = threadIdx.x >> 6;
  const int wr = wave >> 2, wc = wave & 3;
  const int cr = (lane >> 4) * 4, cc = lane & 15;
  u16* C = att + (size_t)z * Sc * Dc;
#pragma unroll
  for (int j = 0; j < 2; ++j) {
    const int gc = col0 + wc * 32 + j * 16 + cc;
#pragma unroll
    for (int i = 0; i < 2; ++i) {
      const int gr = row0 + wr * 32 + i * 16 + cr;
      f32x4 v = acc[i][j];
#pragma unroll
      for (int r = 0; r < 4; ++r) C[(size_t)(gr + r) * Dc + gc] = f2b(v[r]);
    }
  }
}

// ---------------- output = attended @ Wo^T + bo -> fp32 d_out (64x128) ----------------
__global__ __launch_bounds__(512, 4) void gemm_out(const u16* __restrict__ att,
                                                   const u16* __restrict__ Wob,
                                                   const float* __restrict__ bo,
                                                   float* __restrict__ out) {
  __shared__ __align__(16) u16 smem[3 * (64 * 32) + 3 * (128 * 32)];
  int bx, by, bz; xcd_map(bx, by, bz);
  const int row0 = bx * 64, col0 = by * 128;
  f32x4 acc[2][2] = {};
  gemm8<64>(att, Wob, row0, col0, acc, smem);

  const int lane = threadIdx.x & 63, wave = threadIdx.x >> 6;
  const int wr = wave >> 2, wc = wave & 3;
  const int cr = (lane >> 4) * 4, cc = lane & 15;
#pragma unroll
  for (int j = 0; j < 2; ++j) {
    const int gc = col0 + wc * 32 + j * 16 + cc;
    const float bb = bo[gc];
#pragma unroll
    for (int i = 0; i < 2; ++i) {
      const int gr = row0 + wr * 32 + i * 16 + cr;
      f32x4 v = acc[i][j];
#pragma unroll
      for (int r = 0; r < 4; ++r) out[(size_t)(gr + r) * Dc + gc] = v[r] + bb;
    }
  }
}

extern "C" void kernel_launch(void* const* d_in, const int* in_sizes, int n_in,
                              void* d_out, int out_size, void* d_ws, size_t ws_size,
                              hipStream_t stream) {
  const float* query = (const float*)d_in[0];
  const float* key   = (const float*)d_in[1];
  const float* value = (const float*)d_in[2];
  const float* Wq = (const float*)d_in[3];
  const float* bq = (const float*)d_in[4];
  const float* Wk = (const float*)d_in[5];
  const float* bk = (const float*)d_in[6];
  const float* Wv = (const float*)d_in[7];
  const float* bv = (const float*)d_in[8];
  const float* Wo = (const float*)d_in[9];
  const float* bo = (const float*)d_in[10];

  float* out    = (float*)d_out;                    // [B,S,D]
  float* attn_f = out + (size_t)NTOK * Dc;          // [B,S,S]

  char* w = (char*)d_ws;
  const size_t MB = 1ull << 20;
  // Lifetime-overlaid layout (~56 MB):
  //  [0,24)MB : qx,kx,vx; then comb fp32 [0,16) + attnb [16,24)
  //  [24,40)MB: Qb,Kb; then attended overlays [24,32)
  //  [40,48)MB: Vt
  //  [48,56)MB: Wq,Wk,Wv,Wo bf16
  //  [56,..)  : entropy aggregates (64 KB)
  u16* qx = (u16*)(w);
  u16* kx = (u16*)(w + 8 * MB);
  u16* vx = (u16*)(w + 16 * MB);
  float* comb = (float*)(w);
  u16* attnb  = (u16*)(w + 16 * MB);
  u16* Qb = (u16*)(w + 24 * MB);            // Kb = Qb + NTOK*Dc
  u16* attended = (u16*)(w + 24 * MB);
  u16* Vt = (u16*)(w + 40 * MB);
  u16* Wb = (u16*)(w + 48 * MB);            // wq,wk,wv,wo contiguous (2MB each)
  float* agg = (float*)(w + 56 * MB);

  // 1. merged casts (3x16MB tokens + 4x4MB weights -> bf16)
  cast_all<<<16384, 256, 0, stream>>>(query, key, value, Wq, Wk, Wv, Wo, qx, kx, vx, Wb);

  // 2. entropy row aggregates
  ent_agg<<<(2 * NTOK) / 256, 256, 0, stream>>>(query, key, agg);

  // 3. Q/K/V projections (z=0,1,2), V written transposed. 768 blocks, 3/CU, 24 waves/CU.
  gemm_proj<<<dim3(32, 8, 3), 512, 0, stream>>>(qx, Wb, bq, bk, bv, Qb, Vt);

  // 4. combined scores. 512 blocks, 2/CU, 16 waves/CU.
  gemm_scores<<<dim3(16, 8, 4), 512, 0, stream>>>(Qb, Qb + (size_t)NTOK * Dc, agg, comb);

  // 5. softmax rows -> attn (fp32 to d_out, bf16 to ws)
  softmax_row<<<NTOK, 256, 0, stream>>>(comb, attn_f, attnb);

  // 6. attended = attn @ V. 512 blocks.
  gemm_av<<<dim3(16, 8, 4), 512, 0, stream>>>(attnb, Vt, attended);

  // 7. output = attended @ Wo^T + bo. 512 blocks.
  gemm_out<<<dim3(64, 8, 1), 512, 0, stream>>>(attended, Wb + 3ull * Dc * Dc, bo, out);

  (void)in_sizes; (void)n_in; (void)out_size; (void)ws_size;
}

// Round 8
// 209.355 us; speedup vs baseline: 1.4425x; 1.0801x over previous
//
#include <hip/hip_runtime.h>

// QuantumAttentionMechanism on MI355X (gfx950)
// B=4, S=1024, D=1024, H=16, NQ=8, HEAD_DIM=64, ALPHA=0.7
//
// Math simplifications (exact up to fp rounding):
//   classical.mean(h) = (Q . K over full D) / (H*sqrt(HEAD_DIM)) = dot/128
//   entropy(i,j) = log(Z) - (Sa_i + Sb_j)/Z,  Z = A_i + B_j  (per-row aggregates, NQ=8)
//   attended = attn @ V (full D), output = attended @ Wo^T + bo.
//
// Round 8: S-GEMMs (scores/av/out) move to BK=64 (16 K-steps, 8 MFMA + 8
// ds_read_b128 per wave per step, uniform 3 loads/thread -> clean vmcnt(3)
// depth-2 counted pipeline, 3 buffers, 72 KB LDS, 2 blocks/CU). Swizzle
// re-derived for 64-elem rows: slot ^= row&7 (both-sides involution).
// Proj unchanged from round 7 (41 us). Epilogues unchanged.

typedef float f32x4 __attribute__((ext_vector_type(4)));
typedef short s16x8 __attribute__((ext_vector_type(8)));
typedef unsigned short u16;

#define Bc 4
#define Sc 1024
#define Dc 1024
#define NTOK (Bc * Sc)          // 4096
#define CSCALE (0.7f / 128.0f)  // ALPHA / (H*sqrt(HEAD_DIM))
#define ESCALE 0.3f             // 1-ALPHA

typedef void __attribute__((address_space(1))) as1_void;
typedef void __attribute__((address_space(3))) as3_void;

__device__ __forceinline__ u16 f2b(float f) {  // fp32 -> bf16 RNE
  union { float f; unsigned u; } v; v.f = f;
  unsigned r = v.u + 0x7fffu + ((v.u >> 16) & 1u);
  return (u16)(r >> 16);
}

// XCD swizzle: chunk the grid across 8 XCDs; decode by-fastest so consecutive
// blocks within an XCD share the same A-row panel (L2 reuse).
__device__ __forceinline__ void xcd_map(int& bx, int& by, int& bz) {
  const int gx = gridDim.x, gy = gridDim.y;
  const int nwg = gx * gy * gridDim.z;        // all grids here are %8 == 0
  const int lid = blockIdx.x + gx * (blockIdx.y + gy * blockIdx.z);
  const int cpx = nwg >> 3;
  const int s = (lid & 7) * cpx + (lid >> 3);
  by = s % gy; const int r = s / gy; bx = r % gx; bz = r / gx;
}

// ---------------- merged fp32 -> bf16 casts (q,k,v,Wq,Wk,Wv,Wo) ----------------
__global__ __launch_bounds__(256) void cast_all(const float* __restrict__ q,
                                                const float* __restrict__ k,
                                                const float* __restrict__ v,
                                                const float* __restrict__ wq,
                                                const float* __restrict__ wk,
                                                const float* __restrict__ wv,
                                                const float* __restrict__ wo,
                                                u16* __restrict__ qx, u16* __restrict__ kx,
                                                u16* __restrict__ vx, u16* __restrict__ Wb) {
  const int i = blockIdx.x * 256 + threadIdx.x;  // float4 index
  const float* src; u16* dst; int off;
  if (i < 3145728) {                      // 3 x 1048576 (token tensors)
    const int t = i >> 20; off = i & 1048575;
    src = (t == 0) ? q : (t == 1) ? k : v;
    dst = (t == 0) ? qx : (t == 1) ? kx : vx;
  } else {                                // 4 x 262144 (weights)
    const int j = i - 3145728; const int t = j >> 18; off = j & 262143;
    src = (t == 0) ? wq : (t == 1) ? wk : (t == 2) ? wv : wo;
    dst = Wb + (size_t)t * Dc * Dc;
  }
  float4 vv = reinterpret_cast<const float4*>(src)[off];
  reinterpret_cast<ushort4*>(dst)[off] =
      make_ushort4(f2b(vv.x), f2b(vv.y), f2b(vv.z), f2b(vv.w));
}

// ---------------- per-row entropy aggregates ----------------
__global__ __launch_bounds__(256) void ent_agg(const float* __restrict__ q,
                                               const float* __restrict__ k,
                                               float* __restrict__ agg) {
  int r = blockIdx.x * 256 + threadIdx.x;
  if (r >= 2 * NTOK) return;
  const float* src = (r < NTOK) ? (q + (size_t)r * Dc) : (k + (size_t)(r - NTOK) * Dc);
  float A = 0.f, Sv = 0.f;
#pragma unroll
  for (int m = 0; m < 8; ++m) {
    float e = tanhf(src[m]);
    float a = __expf(e);
    A += a; Sv += a * e;
  }
  if (r < NTOK) { agg[r] = A; agg[NTOK + r] = Sv; }
  else          { agg[NTOK + r] = A; agg[3 * NTOK + (r - NTOK)] = Sv; }
}

// ------ 8-wave depth-2 counted-pipeline GEMM core, BK=32 (proj): C[128 x 128] ------
template<int BM>
__device__ __forceinline__ void gemm8(const u16* __restrict__ A, const u16* __restrict__ Bt,
                                      int row0, int col0, f32x4 (*acc)[2],
                                      u16* __restrict__ smem) {
  constexpr int MR = BM / 32;
  constexpr int ASZ = BM * 32;
  constexpr int BSZ = 128 * 32;
  constexpr int K = 1024, nk = 32;
  u16* LA = smem;
  u16* LB = smem + 3 * ASZ;
  const int tid = threadIdx.x;
  const int lane = tid & 63, wave = tid >> 6;
  const int wr = wave >> 2, wc = wave & 3;
  const int fr = lane & 15, g = lane >> 4;

  const int rS = tid >> 2;
  const int slS = (tid & 3) ^ ((rS >> 1) & 3);
  const int rA = (BM == 128) ? rS : (rS & 63);
  const u16* gB = Bt + (size_t)(col0 + rS) * K + slS * 8;
  const u16* gA = A + (size_t)(row0 + rA) * K + slS * 8;

  int aoff[MR], boff[2];
#pragma unroll
  for (int i = 0; i < MR; ++i) {
    const int row = wr * (MR * 16) + i * 16 + fr;
    aoff[i] = row * 32 + ((g ^ ((row >> 1) & 3)) << 3);
  }
#pragma unroll
  for (int j = 0; j < 2; ++j) {
    const int row = wc * 32 + j * 16 + fr;
    boff[j] = row * 32 + ((g ^ ((row >> 1) & 3)) << 3);
  }

  auto stage = [&](int idx, int kt) {
    const int ko = kt * 32;
    if (BM == 128 || tid < 256)
      __builtin_amdgcn_global_load_lds((const as1_void*)(gA + ko),
                                       (as3_void*)(&LA[idx * ASZ + tid * 8]), 16, 0, 0);
    __builtin_amdgcn_global_load_lds((const as1_void*)(gB + ko),
                                     (as3_void*)(&LB[idx * BSZ + tid * 8]), 16, 0, 0);
  };
  auto wait_nl = [&]() {
    if constexpr (BM == 128) {
      asm volatile("s_waitcnt vmcnt(2)" ::: "memory");
    } else {
      if (tid < 256) asm volatile("s_waitcnt vmcnt(2)" ::: "memory");
      else           asm volatile("s_waitcnt vmcnt(1)" ::: "memory");
    }
  };

  stage(0, 0);
  stage(1, 1);
  wait_nl();
  __builtin_amdgcn_s_barrier();
  __builtin_amdgcn_sched_barrier(0);

  int c0 = 0, c1 = 1, c2 = 2;
  for (int kt = 0; kt < nk; ++kt) {
    if (kt + 2 < nk) stage(c2, kt + 2);
    const int ab = c0 * ASZ, bb = c0 * BSZ;
    s16x8 af[MR], bfr[2];
#pragma unroll
    for (int i = 0; i < MR; ++i) af[i] = *reinterpret_cast<const s16x8*>(&LA[ab + aoff[i]]);
#pragma unroll
    for (int j = 0; j < 2; ++j) bfr[j] = *reinterpret_cast<const s16x8*>(&LB[bb + boff[j]]);
#pragma unroll
    for (int i = 0; i < MR; ++i)
#pragma unroll
      for (int j = 0; j < 2; ++j)
        acc[i][j] = __builtin_amdgcn_mfma_f32_16x16x32_bf16(af[i], bfr[j], acc[i][j], 0, 0, 0);
    if (kt + 1 < nk) {
      if (kt + 2 < nk) wait_nl();
      else asm volatile("s_waitcnt vmcnt(0)" ::: "memory");
      __builtin_amdgcn_s_barrier();
      __builtin_amdgcn_sched_barrier(0);
    }
    int t = c0; c0 = c1; c1 = c2; c2 = t;
  }
}

// ------ 8-wave BK=64 depth-2 counted-pipeline GEMM core: C[64 x 128], K=1024 ------
// 512 threads, waves 2x4: wave tile 32 x 32 -> acc[2][2]. Uniform 3 loads/thread.
// Swizzle for 64-elem rows: slot(0..7) ^= row&7, both-sides involution.
__device__ __forceinline__ void gemm64(const u16* __restrict__ A, const u16* __restrict__ Bt,
                                       int row0, int col0, f32x4 (*acc)[2],
                                       u16* __restrict__ smem) {
  constexpr int ASZ = 64 * 64;    // 4096 u16 per buffer
  constexpr int BSZ = 128 * 64;   // 8192 u16 per buffer
  constexpr int K = 1024, nk = 16;
  u16* LA = smem;                 // 3 * ASZ
  u16* LB = smem + 3 * ASZ;       // 3 * BSZ
  const int tid = threadIdx.x;
  const int lane = tid & 63, wave = tid >> 6;
  const int wr = wave >> 2, wc = wave & 3;
  const int fr = lane & 15, g = lane >> 4;

  // staging: chunk ci -> row ci>>3, slot ci&7; LDS linear, global source pre-swizzled
  const int rA = tid >> 3, slA = (tid & 7) ^ (rA & 7);
  const u16* gA = A + (size_t)(row0 + rA) * K + slA * 8;
  const int rB0 = tid >> 3, slB0 = (tid & 7) ^ (rB0 & 7);
  const int rB1 = rB0 + 64, slB1 = (tid & 7) ^ (rB1 & 7);
  const u16* gB0 = Bt + (size_t)(col0 + rB0) * K + slB0 * 8;
  const u16* gB1 = Bt + (size_t)(col0 + rB1) * K + slB1 * 8;

  // swizzled ds_read element-offsets: slot = (g + kk*4) ^ (row&7)
  int aoff[2][2], boff[2][2];
#pragma unroll
  for (int kk = 0; kk < 2; ++kk) {
#pragma unroll
    for (int i = 0; i < 2; ++i) {
      const int row = wr * 32 + i * 16 + fr;
      aoff[kk][i] = row * 64 + (((g + kk * 4) ^ (row & 7)) << 3);
    }
#pragma unroll
    for (int j = 0; j < 2; ++j) {
      const int row = wc * 32 + j * 16 + fr;
      boff[kk][j] = row * 64 + (((g + kk * 4) ^ (row & 7)) << 3);
    }
  }

  auto stage = [&](int idx, int kt) {
    const int ko = kt * 64;
    __builtin_amdgcn_global_load_lds((const as1_void*)(gA + ko),
                                     (as3_void*)(&LA[idx * ASZ + tid * 8]), 16, 0, 0);
    __builtin_amdgcn_global_load_lds((const as1_void*)(gB0 + ko),
                                     (as3_void*)(&LB[idx * BSZ + tid * 8]), 16, 0, 0);
    __builtin_amdgcn_global_load_lds((const as1_void*)(gB1 + ko),
                                     (as3_void*)(&LB[idx * BSZ + (512 + tid) * 8]), 16, 0, 0);
  };

  stage(0, 0);
  stage(1, 1);
  asm volatile("s_waitcnt vmcnt(3)" ::: "memory");
  __builtin_amdgcn_s_barrier();
  __builtin_amdgcn_sched_barrier(0);

  int c0 = 0, c1 = 1, c2 = 2;
  for (int kt = 0; kt < nk; ++kt) {
    if (kt + 2 < nk) stage(c2, kt + 2);
    const int ab = c0 * ASZ, bb = c0 * BSZ;
    s16x8 af[2][2], bf[2][2];
#pragma unroll
    for (int kk = 0; kk < 2; ++kk) {
#pragma unroll
      for (int i = 0; i < 2; ++i) af[kk][i] = *reinterpret_cast<const s16x8*>(&LA[ab + aoff[kk][i]]);
#pragma unroll
      for (int j = 0; j < 2; ++j) bf[kk][j] = *reinterpret_cast<const s16x8*>(&LB[bb + boff[kk][j]]);
    }
#pragma unroll
    for (int kk = 0; kk < 2; ++kk)
#pragma unroll
      for (int i = 0; i < 2; ++i)
#pragma unroll
        for (int j = 0; j < 2; ++j)
          acc[i][j] = __builtin_amdgcn_mfma_f32_16x16x32_bf16(af[kk][i], bf[kk][j], acc[i][j], 0, 0, 0);
    if (kt + 1 < nk) {
      if (kt + 2 < nk) asm volatile("s_waitcnt vmcnt(3)" ::: "memory");
      else             asm volatile("s_waitcnt vmcnt(0)" ::: "memory");
      __builtin_amdgcn_s_barrier();
      __builtin_amdgcn_sched_barrier(0);
    }
    int t = c0; c0 = c1; c1 = c2; c2 = t;
  }
}

// ---------------- QKV projections (z=0:Q, 1:K, 2:V-transposed), 128x128 ----------------
__global__ __launch_bounds__(512, 6) void gemm_proj(const u16* __restrict__ Xall,
                                                    const u16* __restrict__ Wall,
                                                    const float* __restrict__ biasq,
                                                    const float* __restrict__ biask,
                                                    const float* __restrict__ biasv,
                                                    u16* __restrict__ QKout,
                                                    u16* __restrict__ Vt) {
  __shared__ __align__(16) u16 smem[3 * (128 * 32) * 2];  // 48 KiB
  int bx, by, z; xcd_map(bx, by, z);
  const int row0 = bx * 128, col0 = by * 128;
  const u16* A  = Xall + (size_t)z * NTOK * Dc;
  const u16* Bt = Wall + (size_t)z * Dc * Dc;
  f32x4 acc[4][2] = {};
  gemm8<128>(A, Bt, row0, col0, acc, smem);

  const int tid = threadIdx.x;
  const int lane = tid & 63, wave = tid >> 6;
  const int wr = wave >> 2, wc = wave & 3;
  const int cr = (lane >> 4) * 4, cc = lane & 15;
  const float* bias = (z == 0) ? biasq : (z == 1) ? biask : biasv;
  if (z < 2) {
#pragma unroll
    for (int j = 0; j < 2; ++j) {
      const int gc = col0 + wc * 32 + j * 16 + cc;
      const float bb = bias[gc];
#pragma unroll
      for (int i = 0; i < 4; ++i) {
        const int gr = row0 + wr * 64 + i * 16 + cr;
        f32x4 v = acc[i][j];
        u16* dst = QKout + (size_t)z * NTOK * Dc + (size_t)gr * Dc + gc;
#pragma unroll
        for (int r = 0; r < 4; ++r) dst[(size_t)r * Dc] = f2b(v[r] + bb);
      }
    }
  } else {
    // transpose through LDS -> coalesced Vt writes
    __syncthreads();                 // all waves done with GEMM LDS reads
    u16* T = smem;                   // [128 d][132 t] bf16, padded stride
#pragma unroll
    for (int j = 0; j < 2; ++j) {
      const int lc = wc * 32 + j * 16 + cc;
      const float bb = bias[col0 + lc];
#pragma unroll
      for (int i = 0; i < 4; ++i) {
        const int lrb = wr * 64 + i * 16 + cr;
        f32x4 v = acc[i][j];
        ushort4 o = make_ushort4(f2b(v[0] + bb), f2b(v[1] + bb), f2b(v[2] + bb), f2b(v[3] + bb));
        *reinterpret_cast<ushort4*>(&T[lc * 132 + lrb]) = o;
      }
    }
    __syncthreads();
    const int d = tid >> 2, q = tid & 3;   // 4 threads per d-column
    const int b = row0 >> 10, t0 = row0 & (Sc - 1);
    u16* dst = Vt + (size_t)b * Dc * Sc + (size_t)(col0 + d) * Sc + t0 + q * 32;
#pragma unroll
    for (int m = 0; m < 8; ++m)  // 8 x ushort4 = 32 t-values
      reinterpret_cast<ushort4*>(dst)[m] = *reinterpret_cast<const ushort4*>(&T[d * 132 + q * 32 + m * 4]);
  }
}

// ---------------- scores GEMM (64x128, BK=64) + entropy epilogue ----------------
__global__ __launch_bounds__(512, 4) void gemm_scores(const u16* __restrict__ Qb,
                                                      const u16* __restrict__ Kb,
                                                      const float* __restrict__ agg,
                                                      float* __restrict__ comb) {
  __shared__ __align__(16) u16 smem[3 * (64 * 64) + 3 * (128 * 64)];  // 72 KiB
  int bx, by, z; xcd_map(bx, by, z);
  const int row0 = bx * 64, col0 = by * 128;
  const u16* A  = Qb + (size_t)z * Sc * Dc;
  const u16* Bt = Kb + (size_t)z * Sc * Dc;
  f32x4 acc[2][2] = {};
  gemm64(A, Bt, row0, col0, acc, smem);

  const int lane = threadIdx.x & 63, wave = threadIdx.x >> 6;
  const int wr = wave >> 2, wc = wave & 3;
  const int cr = (lane >> 4) * 4, cc = lane & 15;
  const float* qA = agg + (size_t)z * Sc;
  const float* qS = agg + NTOK + (size_t)z * Sc;
  const float* kA = agg + 2 * NTOK + (size_t)z * Sc;
  const float* kS = agg + 3 * NTOK + (size_t)z * Sc;
  float* C = comb + (size_t)z * Sc * Sc;
#pragma unroll
  for (int j = 0; j < 2; ++j) {
    const int gc = col0 + wc * 32 + j * 16 + cc;
    const float kAv = kA[gc], kSv = kS[gc];
#pragma unroll
    for (int i = 0; i < 2; ++i) {
      const int gr = row0 + wr * 32 + i * 16 + cr;
      f32x4 v = acc[i][j];
#pragma unroll
      for (int r = 0; r < 4; ++r) {
        const int s = gr + r;
        const float Z = qA[s] + kAv;
        const float ent = __logf(Z) - (qS[s] + kSv) / Z;
        C[(size_t)s * Sc + gc] = CSCALE * v[r] + ESCALE * ent;
      }
    }
  }
}

// ---------------- row softmax: comb -> attn fp32 (d_out) + attn bf16 (ws) ----------------
__global__ __launch_bounds__(256) void softmax_row(const float* __restrict__ comb,
                                                   float* __restrict__ attn_f,
                                                   u16* __restrict__ attn_b) {
  const int row = blockIdx.x;
  const int t = threadIdx.x;
  const float* src = comb + (size_t)row * Sc;
  float4 v = reinterpret_cast<const float4*>(src)[t];
  float m = fmaxf(fmaxf(v.x, v.y), fmaxf(v.z, v.w));
#pragma unroll
  for (int off = 1; off < 64; off <<= 1) m = fmaxf(m, __shfl_xor(m, off));
  __shared__ float red[8];
  if ((t & 63) == 0) red[t >> 6] = m;
  __syncthreads();
  m = fmaxf(fmaxf(red[0], red[1]), fmaxf(red[2], red[3]));
  float e0 = __expf(v.x - m), e1 = __expf(v.y - m), e2 = __expf(v.z - m), e3 = __expf(v.w - m);
  float s = e0 + e1 + e2 + e3;
#pragma unroll
  for (int off = 1; off < 64; off <<= 1) s += __shfl_xor(s, off);
  if ((t & 63) == 0) red[4 + (t >> 6)] = s;
  __syncthreads();
  s = red[4] + red[5] + red[6] + red[7];
  const float inv = 1.f / s;
  float4 o = make_float4(e0 * inv, e1 * inv, e2 * inv, e3 * inv);
  reinterpret_cast<float4*>(attn_f + (size_t)row * Sc)[t] = o;
  ushort4 ob = make_ushort4(f2b(o.x), f2b(o.y), f2b(o.z), f2b(o.w));
  reinterpret_cast<ushort4*>(attn_b + (size_t)row * Sc)[t] = ob;
}

// ---------------- attended = attn @ V  (64x128 BK=64, Bt = Vt[b][d][t]) ----------------
__global__ __launch_bounds__(512, 4) void gemm_av(const u16* __restrict__ attnb,
                                                  const u16* __restrict__ Vt,
                                                  u16* __restrict__ att) {
  __shared__ __align__(16) u16 smem[3 * (64 * 64) + 3 * (128 * 64)];
  int bx, by, z; xcd_map(bx, by, z);
  const int row0 = bx * 64, col0 = by * 128;
  const u16* A  = attnb + (size_t)z * Sc * Sc;
  const u16* Bt = Vt + (size_t)z * Dc * Sc;
  f32x4 acc[2][2] = {};
  gemm64(A, Bt, row0, col0, acc, smem);

  const int lane = threadIdx.x & 63, wave = threadIdx.x >> 6;
  const int wr = wave >> 2, wc = wave & 3;
  const int cr = (lane >> 4) * 4, cc = lane & 15;
  u16* C = att + (size_t)z * Sc * Dc;
#pragma unroll
  for (int j = 0; j < 2; ++j) {
    const int gc = col0 + wc * 32 + j * 16 + cc;
#pragma unroll
    for (int i = 0; i < 2; ++i) {
      const int gr = row0 + wr * 32 + i * 16 + cr;
      f32x4 v = acc[i][j];
#pragma unroll
      for (int r = 0; r < 4; ++r) C[(size_t)(gr + r) * Dc + gc] = f2b(v[r]);
    }
  }
}

// ---------------- output = attended @ Wo^T + bo -> fp32 d_out (64x128 BK=64) ----------------
__global__ __launch_bounds__(512, 4) void gemm_out(const u16* __restrict__ att,
                                                   const u16* __restrict__ Wob,
                                                   const float* __restrict__ bo,
                                                   float* __restrict__ out) {
  __shared__ __align__(16) u16 smem[3 * (64 * 64) + 3 * (128 * 64)];
  int bx, by, bz; xcd_map(bx, by, bz);
  const int row0 = bx * 64, col0 = by * 128;
  f32x4 acc[2][2] = {};
  gemm64(att, Wob, row0, col0, acc, smem);

  const int lane = threadIdx.x & 63, wave = threadIdx.x >> 6;
  const int wr = wave >> 2, wc = wave & 3;
  const int cr = (lane >> 4) * 4, cc = lane & 15;
#pragma unroll
  for (int j = 0; j < 2; ++j) {
    const int gc = col0 + wc * 32 + j * 16 + cc;
    const float bb = bo[gc];
#pragma unroll
    for (int i = 0; i < 2; ++i) {
      const int gr = row0 + wr * 32 + i * 16 + cr;
      f32x4 v = acc[i][j];
#pragma unroll
      for (int r = 0; r < 4; ++r) out[(size_t)(gr + r) * Dc + gc] = v[r] + bb;
    }
  }
}

extern "C" void kernel_launch(void* const* d_in, const int* in_sizes, int n_in,
                              void* d_out, int out_size, void* d_ws, size_t ws_size,
                              hipStream_t stream) {
  const float* query = (const float*)d_in[0];
  const float* key   = (const float*)d_in[1];
  const float* value = (const float*)d_in[2];
  const float* Wq = (const float*)d_in[3];
  const float* bq = (const float*)d_in[4];
  const float* Wk = (const float*)d_in[5];
  const float* bk = (const float*)d_in[6];
  const float* Wv = (const float*)d_in[7];
  const float* bv = (const float*)d_in[8];
  const float* Wo = (const float*)d_in[9];
  const float* bo = (const float*)d_in[10];

  float* out    = (float*)d_out;                    // [B,S,D]
  float* attn_f = out + (size_t)NTOK * Dc;          // [B,S,S]

  char* w = (char*)d_ws;
  const size_t MB = 1ull << 20;
  // Lifetime-overlaid layout (~56 MB):
  //  [0,24)MB : qx,kx,vx; then comb fp32 [0,16) + attnb [16,24)
  //  [24,40)MB: Qb,Kb; then attended overlays [24,32)
  //  [40,48)MB: Vt
  //  [48,56)MB: Wq,Wk,Wv,Wo bf16
  //  [56,..)  : entropy aggregates (64 KB)
  u16* qx = (u16*)(w);
  u16* kx = (u16*)(w + 8 * MB);
  u16* vx = (u16*)(w + 16 * MB);
  float* comb = (float*)(w);
  u16* attnb  = (u16*)(w + 16 * MB);
  u16* Qb = (u16*)(w + 24 * MB);            // Kb = Qb + NTOK*Dc
  u16* attended = (u16*)(w + 24 * MB);
  u16* Vt = (u16*)(w + 40 * MB);
  u16* Wb = (u16*)(w + 48 * MB);            // wq,wk,wv,wo contiguous (2MB each)
  float* agg = (float*)(w + 56 * MB);

  // 1. merged casts (3x16MB tokens + 4x4MB weights -> bf16)
  cast_all<<<16384, 256, 0, stream>>>(query, key, value, Wq, Wk, Wv, Wo, qx, kx, vx, Wb);

  // 2. entropy row aggregates
  ent_agg<<<(2 * NTOK) / 256, 256, 0, stream>>>(query, key, agg);

  // 3. Q/K/V projections (z=0,1,2), V written transposed. 768 blocks, 3/CU.
  gemm_proj<<<dim3(32, 8, 3), 512, 0, stream>>>(qx, Wb, bq, bk, bv, Qb, Vt);

  // 4. combined scores. 512 blocks, 2/CU, BK=64.
  gemm_scores<<<dim3(16, 8, 4), 512, 0, stream>>>(Qb, Qb + (size_t)NTOK * Dc, agg, comb);

  // 5. softmax rows -> attn (fp32 to d_out, bf16 to ws)
  softmax_row<<<NTOK, 256, 0, stream>>>(comb, attn_f, attnb);

  // 6. attended = attn @ V. 512 blocks, BK=64.
  gemm_av<<<dim3(16, 8, 4), 512, 0, stream>>>(attnb, Vt, attended);

  // 7. output = attended @ Wo^T + bo. 512 blocks, BK=64.
  gemm_out<<<dim3(64, 8, 1), 512, 0, stream>>>(attended, Wb + 3ull * Dc * Dc, bo, out);

  (void)in_sizes; (void)n_in; (void)out_size; (void)ws_size;
}